// Round 1
// baseline (22651.965 us; speedup 1.0000x reference)
//
#include <hip/hip_runtime.h>
#include <hip/hip_bf16.h>
#include <math.h>

#define B_   8
#define N_   256
#define L_   6
#define D_   512
#define NT_  2048   // B_*N_
#define HID_ 2048
#define KP_  588    // 14*14*3

// ---------------------------------------------------------------------------
// Generic NN tiled GEMM: C[m][n] = f( sum_k A[m][k]*B[k][n] )
// 64x64 tile, 256 threads, 4x4 microtile, BK=16.
// A staged k-major (As[k][row], padded) so inner loop uses float4 LDS reads.
// Optional: pos added to A rows (pos[(row%256)*512+k]); optional exact GELU.
// z-batching: A += z*az;  B/C offset via (z/zdiv)*xz1 + (z%zdiv)*xz2.
// ---------------------------------------------------------------------------
__global__ __launch_bounds__(256) void gemm_nn(
    const float* __restrict__ A, int lda, long az,
    const float* __restrict__ Bm, int ldb, long bz1, long bz2,
    float* __restrict__ C, int ldc, long cz1, long cz2, int zdiv,
    int K, const float* __restrict__ pos, int do_gelu)
{
    const int z = blockIdx.z;
    A += (long)z * az;
    const int zq = z / zdiv, zr = z - zq * zdiv;
    Bm += (long)zq * bz1 + (long)zr * bz2;
    C  += (long)zq * cz1 + (long)zr * cz2;

    __shared__ float As[16][68];   // k-major, padded (272B rows: 16B aligned)
    __shared__ float Bs[16][64];

    const int tid = threadIdx.x;
    const int tx = tid & 15, ty = tid >> 4;
    const int m0 = blockIdx.y * 64, n0 = blockIdx.x * 64;

    const int arow = tid >> 2, akc = (tid & 3) * 4;
    const int brow = tid >> 4, bcol = (tid & 15) * 4;

    float acc[4][4] = {};

    for (int k0 = 0; k0 < K; k0 += 16) {
        float4 av = *(const float4*)&A[(long)(m0 + arow) * lda + k0 + akc];
        if (pos) {
            const float4 pv = *(const float4*)&pos[(long)((m0 + arow) & 255) * 512 + k0 + akc];
            av.x += pv.x; av.y += pv.y; av.z += pv.z; av.w += pv.w;
        }
        const float4 bv = *(const float4*)&Bm[(long)(k0 + brow) * ldb + n0 + bcol];

        __syncthreads();
        As[akc + 0][arow] = av.x;
        As[akc + 1][arow] = av.y;
        As[akc + 2][arow] = av.z;
        As[akc + 3][arow] = av.w;
        *(float4*)&Bs[brow][bcol] = bv;
        __syncthreads();

#pragma unroll
        for (int k = 0; k < 16; ++k) {
            const float4 a  = *(const float4*)&As[k][ty * 4];
            const float4 bb = *(const float4*)&Bs[k][tx * 4];
            const float ar[4] = {a.x, a.y, a.z, a.w};
            const float br[4] = {bb.x, bb.y, bb.z, bb.w};
#pragma unroll
            for (int i = 0; i < 4; ++i)
#pragma unroll
                for (int j = 0; j < 4; ++j)
                    acc[i][j] = fmaf(ar[i], br[j], acc[i][j]);
        }
    }

#pragma unroll
    for (int i = 0; i < 4; ++i) {
        float4 o;
        float* op = &o.x;
#pragma unroll
        for (int j = 0; j < 4; ++j) {
            float v = acc[i][j];
            if (do_gelu) v = 0.5f * v * (1.0f + erff(v * 0.70710678118654752f));
            op[j] = v;
        }
        *(float4*)&C[(long)(m0 + ty * 4 + i) * ldc + n0 + tx * 4] = o;
    }
}

// ---------------------------------------------------------------------------
// Consensus similarity (NT gemm): per z=(b*6+l):
//   sim[i][j] = dot(lev[b,i,l,:], lev[b,j,l,:]) * invnorm[b,j,l] / sqrt(512)
//   sim[i][i] = -0.0005
// ---------------------------------------------------------------------------
__global__ __launch_bounds__(256) void sim_kernel(
    const float* __restrict__ levels, const float* __restrict__ invn,
    float* __restrict__ sim)
{
    const int z = blockIdx.z;
    const int b = z / 6, l = z - 6 * b;
    const float* base = levels + ((long)b * N_ * L_ + l) * D_;  // row stride 3072

    __shared__ float As[16][68];
    __shared__ float Bs[16][68];

    const int tid = threadIdx.x;
    const int tx = tid & 15, ty = tid >> 4;
    const int m0 = blockIdx.y * 64, n0 = blockIdx.x * 64;
    const int arow = tid >> 2, akc = (tid & 3) * 4;

    float acc[4][4] = {};

    for (int k0 = 0; k0 < 512; k0 += 16) {
        const float4 av = *(const float4*)&base[(long)(m0 + arow) * 3072 + k0 + akc];
        const float4 bv = *(const float4*)&base[(long)(n0 + arow) * 3072 + k0 + akc];
        __syncthreads();
        As[akc + 0][arow] = av.x; As[akc + 1][arow] = av.y;
        As[akc + 2][arow] = av.z; As[akc + 3][arow] = av.w;
        Bs[akc + 0][arow] = bv.x; Bs[akc + 1][arow] = bv.y;
        Bs[akc + 2][arow] = bv.z; Bs[akc + 3][arow] = bv.w;
        __syncthreads();
#pragma unroll
        for (int k = 0; k < 16; ++k) {
            const float4 a  = *(const float4*)&As[k][ty * 4];
            const float4 bb = *(const float4*)&Bs[k][tx * 4];
            const float ar[4] = {a.x, a.y, a.z, a.w};
            const float br[4] = {bb.x, bb.y, bb.z, bb.w};
#pragma unroll
            for (int i = 0; i < 4; ++i)
#pragma unroll
                for (int j = 0; j < 4; ++j)
                    acc[i][j] = fmaf(ar[i], br[j], acc[i][j]);
        }
    }

    const float sc = 0.044194173824159216f;  // 512^-0.5
#pragma unroll
    for (int i = 0; i < 4; ++i) {
        const int ig = m0 + ty * 4 + i;
        float4 o; float* op = &o.x;
#pragma unroll
        for (int j = 0; j < 4; ++j) {
            const int jg = n0 + tx * 4 + j;
            float v = acc[i][j] * invn[((long)b * N_ + jg) * L_ + l] * sc;
            if (ig == jg) v = -0.0005f;
            op[j] = v;
        }
        *(float4*)&sim[((long)z * N_ + ig) * N_ + n0 + tx * 4] = o;
    }
}

// one wave per (t,l) row of 512: inverse norms
__global__ __launch_bounds__(256) void invnorm_kernel(
    const float* __restrict__ levels, float* __restrict__ invn)
{
    const int wid = blockIdx.x * 4 + (threadIdx.x >> 6);
    const int lane = threadIdx.x & 63;
    const float* row = levels + (long)wid * 512;
    float s = 0.f;
#pragma unroll
    for (int k = lane * 4; k < 512; k += 256) {
        const float4 v = *(const float4*)&row[k];
        s += v.x * v.x + v.y * v.y + v.z * v.z + v.w * v.w;
    }
#pragma unroll
    for (int o = 1; o < 64; o <<= 1) s += __shfl_xor(s, o);
    if (lane == 0) invn[wid] = 1.0f / fmaxf(sqrtf(s), 1e-12f);
}

// one wave per row of 256 (in-place)
__global__ __launch_bounds__(256) void softmax_kernel(float* __restrict__ sim)
{
    const long row = (long)blockIdx.x * 4 + (threadIdx.x >> 6);
    const int lane = threadIdx.x & 63;
    float* p = sim + row * 256;
    float4 v = *(float4*)&p[lane * 4];
    float m = fmaxf(fmaxf(v.x, v.y), fmaxf(v.z, v.w));
#pragma unroll
    for (int o = 1; o < 64; o <<= 1) m = fmaxf(m, __shfl_xor(m, o));
    v.x = expf(v.x - m); v.y = expf(v.y - m);
    v.z = expf(v.z - m); v.w = expf(v.w - m);
    float s = v.x + v.y + v.z + v.w;
#pragma unroll
    for (int o = 1; o < 64; o <<= 1) s += __shfl_xor(s, o);
    const float inv = 1.0f / s;
    v.x *= inv; v.y *= inv; v.z *= inv; v.w *= inv;
    *(float4*)&p[lane * 4] = v;
}

// tokens = patchify(img) @ W_patch + b_patch ; one block per token
__global__ __launch_bounds__(256) void patch_embed(
    const float* __restrict__ img, const float* __restrict__ Wp,
    const float* __restrict__ bp, float* __restrict__ tokens)
{
    __shared__ float xrow[KP_];
    const int t = blockIdx.x;
    const int b = t >> 8, n = t & 255;
    const int hh = n >> 4, ww = n & 15;
    for (int k = threadIdx.x; k < KP_; k += 256) {
        const int c = k % 3;
        const int pj = (k / 3) % 14;
        const int pi = k / 42;
        xrow[k] = img[(((long)b * 3 + c) * 224 + (hh * 14 + pi)) * 224 + (ww * 14 + pj)];
    }
    __syncthreads();
    const int d = threadIdx.x;
    float a0 = bp[d], a1 = bp[d + 256];
    for (int k = 0; k < KP_; ++k) {
        const float xv = xrow[k];
        a0 = fmaf(xv, Wp[(long)k * 512 + d], a0);
        a1 = fmaf(xv, Wp[(long)k * 512 + d + 256], a1);
    }
    tokens[(long)t * 512 + d] = a0;
    tokens[(long)t * 512 + d + 256] = a1;
}

__global__ __launch_bounds__(256) void init_levels_kernel(
    float* __restrict__ levels, const float* __restrict__ initlv)
{
    const long f = (long)blockIdx.x * 256 + threadIdx.x;  // float4 index
    const int d4 = f & 127;
    const int l = (int)((f >> 7) % 6);
    *(float4*)&levels[f * 4] = *(const float4*)&initlv[(long)l * 512 + d4 * 4];
}

// levels = (levels + bu_cat + td_pad + cons) * 0.25
__global__ __launch_bounds__(256) void update_kernel(
    float* __restrict__ levels, const float* __restrict__ tokens,
    const float* __restrict__ bu, const float* __restrict__ td,
    const float* __restrict__ cons)
{
    const long f = (long)blockIdx.x * 256 + threadIdx.x;  // float4 index
    const int d4 = f & 127;
    const long tl = f >> 7;
    const int l = (int)(tl % 6);
    const long t = tl / 6;
    const long off = f * 4;

    float4 lev = *(float4*)&levels[off];
    const float4 cns = *(const float4*)&cons[off];
    float4 but;
    if (l == 0) but = *(const float4*)&tokens[t * 512 + d4 * 4];
    else        but = *(const float4*)&bu[((long)(l - 1) * NT_ + t) * 512 + d4 * 4];
    float4 tdt = make_float4(0.f, 0.f, 0.f, 0.f);
    if (l < 5)  tdt = *(const float4*)&td[((long)l * NT_ + t) * 512 + d4 * 4];

    lev.x = (lev.x + but.x + tdt.x + cns.x) * 0.25f;
    lev.y = (lev.y + but.y + tdt.y + cns.y) * 0.25f;
    lev.z = (lev.z + but.z + tdt.z + cns.z) * 0.25f;
    lev.w = (lev.w + but.w + tdt.w + cns.w) * 0.25f;
    *(float4*)&levels[off] = lev;
}

extern "C" void kernel_launch(void* const* d_in, const int* in_sizes, int n_in,
                              void* d_out, int out_size, void* d_ws, size_t ws_size,
                              hipStream_t stream)
{
    const float* img    = (const float*)d_in[0];
    const float* Wp     = (const float*)d_in[1];
    const float* bp     = (const float*)d_in[2];
    const float* pos    = (const float*)d_in[3];
    const float* initlv = (const float*)d_in[4];
    const float* bu_in  = (const float*)d_in[5];
    const float* bu_out = (const float*)d_in[6];
    const float* td_in  = (const float*)d_in[7];
    const float* td_out = (const float*)d_in[8];

    float* levels = (float*)d_out;              // (2048, 6, 512)
    float* ws = (float*)d_ws;
    float* tokens = ws;                         // 1,048,576
    float* h      = tokens + 1048576;           // 4,194,304 (one level, reused)
    float* bu     = h + 4194304;                // 5,242,880  [l][t][512]
    float* td     = bu + 5242880;               // 5,242,880  [l][t][512]
    float* cons   = td + 5242880;               // 6,291,456  same layout as levels
    float* sim    = cons + 6291456;             // 3,145,728  [z=48][256][256]
    float* invn   = sim + 3145728;              // 12,288

    init_levels_kernel<<<6144, 256, 0, stream>>>(levels, initlv);
    patch_embed<<<NT_, 256, 0, stream>>>(img, Wp, bp, tokens);

    for (int it = 0; it < 12; ++it) {
        for (int l = 0; l < 5; ++l) {
            // bu: in = levels[:, :, l, :]
            gemm_nn<<<dim3(32, 32, 1), 256, 0, stream>>>(
                levels + (long)l * D_, L_ * D_, 0,
                bu_in + (long)l * D_ * HID_, HID_, 0, 0,
                h, HID_, 0, 0, 1, D_, nullptr, 1);
            gemm_nn<<<dim3(8, 32, 1), 256, 0, stream>>>(
                h, HID_, 0,
                bu_out + (long)l * HID_ * D_, D_, 0, 0,
                bu + (long)l * NT_ * D_, D_, 0, 0, 1, HID_, nullptr, 0);
            // td: in = levels[:, :, l+1, :] + pos
            gemm_nn<<<dim3(32, 32, 1), 256, 0, stream>>>(
                levels + (long)(l + 1) * D_, L_ * D_, 0,
                td_in + (long)l * D_ * HID_, HID_, 0, 0,
                h, HID_, 0, 0, 1, D_, pos, 1);
            gemm_nn<<<dim3(8, 32, 1), 256, 0, stream>>>(
                h, HID_, 0,
                td_out + (long)l * HID_ * D_, D_, 0, 0,
                td + (long)l * NT_ * D_, D_, 0, 0, 1, HID_, nullptr, 0);
        }
        invnorm_kernel<<<3072, 256, 0, stream>>>(levels, invn);
        sim_kernel<<<dim3(4, 4, 48), 256, 0, stream>>>(levels, invn, sim);
        softmax_kernel<<<3072, 256, 0, stream>>>(sim);
        // cons: per z=(b*6+l): attn(256x256) @ levels_b,l (256x512)
        gemm_nn<<<dim3(8, 4, 48), 256, 0, stream>>>(
            sim, N_, (long)N_ * N_,
            levels, L_ * D_, (long)N_ * L_ * D_, D_,
            cons, L_ * D_, (long)N_ * L_ * D_, D_, 6,
            N_, nullptr, 0);
        update_kernel<<<6144, 256, 0, stream>>>(levels, tokens, bu, td, cons);
    }
}

// Round 2
// 4211.150 us; speedup vs baseline: 5.3790x; 5.3790x over previous
//
#include <hip/hip_runtime.h>
#include <hip/hip_bf16.h>
#include <math.h>

#define B_   8
#define N_   256
#define L_   6
#define D_   512
#define NT_  2048   // B_*N_
#define HID_ 2048
#define KP_  588    // 14*14*3

typedef __attribute__((ext_vector_type(4))) float f32x4;
typedef __attribute__((ext_vector_type(8))) short bf16x8;

struct bf16x4s { __hip_bfloat16 x, y, z, w; };

__device__ __forceinline__ bf16x4s to_bf4(float a, float b, float c, float d) {
    bf16x4s r;
    r.x = __float2bfloat16(a); r.y = __float2bfloat16(b);
    r.z = __float2bfloat16(c); r.w = __float2bfloat16(d);
    return r;
}

__device__ __forceinline__ void gload16(const void* g, void* l) {
    __builtin_amdgcn_global_load_lds(
        (const __attribute__((address_space(1))) int*)g,
        (__attribute__((address_space(3))) int*)l, 16, 0, 0);
}

// ---------------------------------------------------------------------------
// bf16 MFMA GEMM, both operands K-contiguous row-major ("TN" fragment style):
//   A: M x K (lda), B(transposed weights): N x K (ldb), C: M x N (ldc)
// 128x128 tile, BK=32, 256 threads = 4 waves (2x2), 4x4 frags of 16x16x32.
// LDS [128][32] bf16 per operand; 16B-slot XOR swizzle (slot ^= (row>>1)&3)
// applied on BOTH global_load_lds source and ds_read addr (rule #21).
// ---------------------------------------------------------------------------
template<typename CT, bool GELU, bool ACCUM>
__global__ __launch_bounds__(256) void gemm_mfma(
    const __hip_bfloat16* __restrict__ A, int lda, long az,
    const __hip_bfloat16* __restrict__ B, int ldb, long bz,
    CT* __restrict__ C, int ldc, long cz, int K)
{
    __shared__ short As[128 * 32];
    __shared__ short Bs[128 * 32];

    const int tid = threadIdx.x;
    const int wave = tid >> 6, lane = tid & 63;
    const int z = blockIdx.z;
    A += (long)z * az;  B += (long)z * bz;  C += (long)z * cz;
    const int m0 = blockIdx.y * 128, n0 = blockIdx.x * 128;
    const int wm = (wave >> 1) * 64, wn = (wave & 1) * 64;

    const int srow_in = lane >> 2;   // 0..15 within a 16-row group
    const int sslot   = lane & 3;    // which 16B (8 bf16) slot of the 64B row

    f32x4 acc[4][4] = {};

    for (int k0 = 0; k0 < K; k0 += 32) {
        __syncthreads();   // prior-tile LDS reads done before overwrite
#pragma unroll
        for (int c = 0; c < 2; ++c) {
            const int rbase = c * 64 + wave * 16;      // wave-uniform
            const int row   = rbase + srow_in;
            const int gk    = sslot ^ ((row >> 1) & 3);
            gload16(A + (long)(m0 + row) * lda + k0 + gk * 8, As + rbase * 32);
            gload16(B + (long)(n0 + row) * ldb + k0 + gk * 8, Bs + rbase * 32);
        }
        __syncthreads();   // drains vmcnt (compiler-inserted) before reads

        const int fr = lane & 15, ksub = lane >> 4;
        bf16x8 af[4], bfr[4];
#pragma unroll
        for (int i = 0; i < 4; ++i) {
            const int ra = wm + i * 16 + fr;
            af[i]  = *(const bf16x8*)(As + ra * 32 + (ksub ^ ((ra >> 1) & 3)) * 8);
            const int rb = wn + i * 16 + fr;
            bfr[i] = *(const bf16x8*)(Bs + rb * 32 + (ksub ^ ((rb >> 1) & 3)) * 8);
        }
#pragma unroll
        for (int i = 0; i < 4; ++i)
#pragma unroll
            for (int j = 0; j < 4; ++j)
                acc[i][j] = __builtin_amdgcn_mfma_f32_16x16x32_bf16(
                    af[i], bfr[j], acc[i][j], 0, 0, 0);
    }

    // C/D layout (m89-verified): col = lane&15, row = (lane>>4)*4 + reg
    const int cr = lane >> 4, cc = lane & 15;
#pragma unroll
    for (int i = 0; i < 4; ++i)
#pragma unroll
        for (int j = 0; j < 4; ++j) {
            const int col = n0 + wn + j * 16 + cc;
#pragma unroll
            for (int r = 0; r < 4; ++r) {
                const int row = m0 + wm + i * 16 + cr * 4 + r;
                float v = acc[i][j][r];
                if (GELU) v = 0.5f * v * (1.0f + erff(v * 0.70710678118654752f));
                CT* p = &C[(long)row * ldc + col];
                if constexpr (ACCUM) *p = *p + (CT)v;
                else if constexpr (sizeof(CT) == 2) *p = __float2bfloat16(v);
                else *p = (CT)v;
            }
        }
}

// 32x32 LDS tile transpose, fp32 -> bf16:  dst[c][r] = src[r][c]
__global__ __launch_bounds__(256) void transpose_to_bf16(
    const float* __restrict__ src, __hip_bfloat16* __restrict__ dst,
    int R, int Cc)
{
    __shared__ float t[32][33];
    const int zz = blockIdx.z;
    src += (long)zz * R * Cc;  dst += (long)zz * R * Cc;
    const int tx = threadIdx.x & 31, ty = threadIdx.x >> 5;
    const int c0 = blockIdx.x * 32, r0 = blockIdx.y * 32;
#pragma unroll
    for (int i = 0; i < 4; ++i)
        t[ty + i * 8][tx] = src[(long)(r0 + ty + i * 8) * Cc + c0 + tx];
    __syncthreads();
#pragma unroll
    for (int i = 0; i < 4; ++i)
        dst[(long)(c0 + ty + i * 8) * R + r0 + tx] = __float2bfloat16(t[tx][ty + i * 8]);
}

// ---------------------------------------------------------------------------
// fp32 consensus kernels (unchanged from verified round-0 versions)
// ---------------------------------------------------------------------------
__global__ __launch_bounds__(256) void gemm_nn(
    const float* __restrict__ A, int lda, long az,
    const float* __restrict__ Bm, int ldb, long bz1, long bz2,
    float* __restrict__ C, int ldc, long cz1, long cz2, int zdiv, int K)
{
    const int z = blockIdx.z;
    A += (long)z * az;
    const int zq = z / zdiv, zr = z - zq * zdiv;
    Bm += (long)zq * bz1 + (long)zr * bz2;
    C  += (long)zq * cz1 + (long)zr * cz2;

    __shared__ float As[16][68];
    __shared__ float Bs[16][64];

    const int tid = threadIdx.x;
    const int tx = tid & 15, ty = tid >> 4;
    const int m0 = blockIdx.y * 64, n0 = blockIdx.x * 64;
    const int arow = tid >> 2, akc = (tid & 3) * 4;
    const int brow = tid >> 4, bcol = (tid & 15) * 4;

    float acc[4][4] = {};

    for (int k0 = 0; k0 < K; k0 += 16) {
        const float4 av = *(const float4*)&A[(long)(m0 + arow) * lda + k0 + akc];
        const float4 bv = *(const float4*)&Bm[(long)(k0 + brow) * ldb + n0 + bcol];
        __syncthreads();
        As[akc + 0][arow] = av.x; As[akc + 1][arow] = av.y;
        As[akc + 2][arow] = av.z; As[akc + 3][arow] = av.w;
        *(float4*)&Bs[brow][bcol] = bv;
        __syncthreads();
#pragma unroll
        for (int k = 0; k < 16; ++k) {
            const float4 a  = *(const float4*)&As[k][ty * 4];
            const float4 bb = *(const float4*)&Bs[k][tx * 4];
            const float ar[4] = {a.x, a.y, a.z, a.w};
            const float br[4] = {bb.x, bb.y, bb.z, bb.w};
#pragma unroll
            for (int i = 0; i < 4; ++i)
#pragma unroll
                for (int j = 0; j < 4; ++j)
                    acc[i][j] = fmaf(ar[i], br[j], acc[i][j]);
        }
    }
#pragma unroll
    for (int i = 0; i < 4; ++i) {
        float4 o; float* op = &o.x;
#pragma unroll
        for (int j = 0; j < 4; ++j) op[j] = acc[i][j];
        *(float4*)&C[(long)(m0 + ty * 4 + i) * ldc + n0 + tx * 4] = o;
    }
}

__global__ __launch_bounds__(256) void sim_kernel(
    const float* __restrict__ levels, const float* __restrict__ invn,
    float* __restrict__ sim)
{
    const int z = blockIdx.z;
    const int b = z / 6, l = z - 6 * b;
    const float* base = levels + ((long)b * N_ * L_ + l) * D_;

    __shared__ float As[16][68];
    __shared__ float Bs[16][68];

    const int tid = threadIdx.x;
    const int tx = tid & 15, ty = tid >> 4;
    const int m0 = blockIdx.y * 64, n0 = blockIdx.x * 64;
    const int arow = tid >> 2, akc = (tid & 3) * 4;

    float acc[4][4] = {};

    for (int k0 = 0; k0 < 512; k0 += 16) {
        const float4 av = *(const float4*)&base[(long)(m0 + arow) * 3072 + k0 + akc];
        const float4 bv = *(const float4*)&base[(long)(n0 + arow) * 3072 + k0 + akc];
        __syncthreads();
        As[akc + 0][arow] = av.x; As[akc + 1][arow] = av.y;
        As[akc + 2][arow] = av.z; As[akc + 3][arow] = av.w;
        Bs[akc + 0][arow] = bv.x; Bs[akc + 1][arow] = bv.y;
        Bs[akc + 2][arow] = bv.z; Bs[akc + 3][arow] = bv.w;
        __syncthreads();
#pragma unroll
        for (int k = 0; k < 16; ++k) {
            const float4 a  = *(const float4*)&As[k][ty * 4];
            const float4 bb = *(const float4*)&Bs[k][tx * 4];
            const float ar[4] = {a.x, a.y, a.z, a.w};
            const float br[4] = {bb.x, bb.y, bb.z, bb.w};
#pragma unroll
            for (int i = 0; i < 4; ++i)
#pragma unroll
                for (int j = 0; j < 4; ++j)
                    acc[i][j] = fmaf(ar[i], br[j], acc[i][j]);
        }
    }

    const float sc = 0.044194173824159216f;
#pragma unroll
    for (int i = 0; i < 4; ++i) {
        const int ig = m0 + ty * 4 + i;
        float4 o; float* op = &o.x;
#pragma unroll
        for (int j = 0; j < 4; ++j) {
            const int jg = n0 + tx * 4 + j;
            float v = acc[i][j] * invn[((long)b * N_ + jg) * L_ + l] * sc;
            if (ig == jg) v = -0.0005f;
            op[j] = v;
        }
        *(float4*)&sim[((long)z * N_ + ig) * N_ + n0 + tx * 4] = o;
    }
}

__global__ __launch_bounds__(256) void invnorm_kernel(
    const float* __restrict__ levels, float* __restrict__ invn)
{
    const int wid = blockIdx.x * 4 + (threadIdx.x >> 6);
    const int lane = threadIdx.x & 63;
    const float* row = levels + (long)wid * 512;
    float s = 0.f;
#pragma unroll
    for (int k = lane * 4; k < 512; k += 256) {
        const float4 v = *(const float4*)&row[k];
        s += v.x * v.x + v.y * v.y + v.z * v.z + v.w * v.w;
    }
#pragma unroll
    for (int o = 1; o < 64; o <<= 1) s += __shfl_xor(s, o);
    if (lane == 0) invn[wid] = 1.0f / fmaxf(sqrtf(s), 1e-12f);
}

__global__ __launch_bounds__(256) void softmax_kernel(float* __restrict__ sim)
{
    const long row = (long)blockIdx.x * 4 + (threadIdx.x >> 6);
    const int lane = threadIdx.x & 63;
    float* p = sim + row * 256;
    float4 v = *(float4*)&p[lane * 4];
    float m = fmaxf(fmaxf(v.x, v.y), fmaxf(v.z, v.w));
#pragma unroll
    for (int o = 1; o < 64; o <<= 1) m = fmaxf(m, __shfl_xor(m, o));
    v.x = expf(v.x - m); v.y = expf(v.y - m);
    v.z = expf(v.z - m); v.w = expf(v.w - m);
    float s = v.x + v.y + v.z + v.w;
#pragma unroll
    for (int o = 1; o < 64; o <<= 1) s += __shfl_xor(s, o);
    const float inv = 1.0f / s;
    v.x *= inv; v.y *= inv; v.z *= inv; v.w *= inv;
    *(float4*)&p[lane * 4] = v;
}

__global__ __launch_bounds__(256) void patch_embed(
    const float* __restrict__ img, const float* __restrict__ Wp,
    const float* __restrict__ bp, float* __restrict__ tokens)
{
    __shared__ float xrow[KP_];
    const int t = blockIdx.x;
    const int b = t >> 8, n = t & 255;
    const int hh = n >> 4, ww = n & 15;
    for (int k = threadIdx.x; k < KP_; k += 256) {
        const int c = k % 3;
        const int pj = (k / 3) % 14;
        const int pi = k / 42;
        xrow[k] = img[(((long)b * 3 + c) * 224 + (hh * 14 + pi)) * 224 + (ww * 14 + pj)];
    }
    __syncthreads();
    const int d = threadIdx.x;
    float a0 = bp[d], a1 = bp[d + 256];
    for (int k = 0; k < KP_; ++k) {
        const float xv = xrow[k];
        a0 = fmaf(xv, Wp[(long)k * 512 + d], a0);
        a1 = fmaf(xv, Wp[(long)k * 512 + d + 256], a1);
    }
    tokens[(long)t * 512 + d] = a0;
    tokens[(long)t * 512 + d + 256] = a1;
}

__global__ __launch_bounds__(256) void init_levels_kernel(
    float* __restrict__ levels, const float* __restrict__ initlv)
{
    const long f = (long)blockIdx.x * 256 + threadIdx.x;
    const int d4 = f & 127;
    const int l = (int)((f >> 7) % 6);
    *(float4*)&levels[f * 4] = *(const float4*)&initlv[(long)l * 512 + d4 * 4];
}

// write lev_bf16 = bf16(levels); lp_bf16[l-1] = bf16(levels[l] + pos), l=1..5
__global__ __launch_bounds__(256) void lev_lp_init(
    const float* __restrict__ levels, const float* __restrict__ pos,
    __hip_bfloat16* __restrict__ lev_bf, __hip_bfloat16* __restrict__ lp_bf)
{
    const long f = (long)blockIdx.x * 256 + threadIdx.x;
    const int d4 = f & 127;
    const long tl = f >> 7;
    const int l = (int)(tl % 6);
    const long t = tl / 6;
    const float4 v = *(const float4*)&levels[f * 4];
    *(bf16x4s*)&lev_bf[f * 4] = to_bf4(v.x, v.y, v.z, v.w);
    if (l >= 1) {
        const float4 p = *(const float4*)&pos[(long)(t & 255) * 512 + d4 * 4];
        *(bf16x4s*)&lp_bf[((t * 5 + l - 1) * 512) + d4 * 4] =
            to_bf4(v.x + p.x, v.y + p.y, v.z + p.z, v.w + p.w);
    }
}

__global__ __launch_bounds__(256) void zero_l0(float* __restrict__ acc)
{
    const long f = (long)blockIdx.x * 256 + threadIdx.x;   // 2048*128
    const long t = f >> 7;
    const int d4 = (int)(f & 127);
    *(float4*)&acc[t * 3072 + d4 * 4] = make_float4(0.f, 0.f, 0.f, 0.f);
}

// levels = (levels + [tokens|bu] + td + cons) * 0.25 ; also refresh bf16 copies
__global__ __launch_bounds__(256) void update_kernel(
    float* __restrict__ levels, const float* __restrict__ tokens,
    const float* __restrict__ acc, const float* __restrict__ cons,
    const float* __restrict__ pos,
    __hip_bfloat16* __restrict__ lev_bf, __hip_bfloat16* __restrict__ lp_bf)
{
    const long f = (long)blockIdx.x * 256 + threadIdx.x;
    const int d4 = f & 127;
    const long tl = f >> 7;
    const int l = (int)(tl % 6);
    const long t = tl / 6;
    const long off = f * 4;

    float4 lev = *(float4*)&levels[off];
    const float4 cns = *(const float4*)&cons[off];
    float4 ac  = *(const float4*)&acc[off];
    if (l == 0) {
        const float4 bot = *(const float4*)&tokens[t * 512 + d4 * 4];
        ac.x += bot.x; ac.y += bot.y; ac.z += bot.z; ac.w += bot.w;
    }
    lev.x = (lev.x + ac.x + cns.x) * 0.25f;
    lev.y = (lev.y + ac.y + cns.y) * 0.25f;
    lev.z = (lev.z + ac.z + cns.z) * 0.25f;
    lev.w = (lev.w + ac.w + cns.w) * 0.25f;
    *(float4*)&levels[off] = lev;
    *(bf16x4s*)&lev_bf[off] = to_bf4(lev.x, lev.y, lev.z, lev.w);
    if (l >= 1) {
        const float4 p = *(const float4*)&pos[(long)(t & 255) * 512 + d4 * 4];
        *(bf16x4s*)&lp_bf[((t * 5 + l - 1) * 512) + d4 * 4] =
            to_bf4(lev.x + p.x, lev.y + p.y, lev.z + p.z, lev.w + p.w);
    }
}

extern "C" void kernel_launch(void* const* d_in, const int* in_sizes, int n_in,
                              void* d_out, int out_size, void* d_ws, size_t ws_size,
                              hipStream_t stream)
{
    const float* img    = (const float*)d_in[0];
    const float* Wp     = (const float*)d_in[1];
    const float* bp     = (const float*)d_in[2];
    const float* pos    = (const float*)d_in[3];
    const float* initlv = (const float*)d_in[4];
    const float* bu_in  = (const float*)d_in[5];
    const float* bu_out = (const float*)d_in[6];
    const float* td_in  = (const float*)d_in[7];
    const float* td_out = (const float*)d_in[8];

    float* levels = (float*)d_out;                 // [2048][6][512] fp32
    float* ws = (float*)d_ws;
    float* tokens  = ws;                           // 1,048,576 f
    float* acc     = tokens + 1048576;             // 6,291,456 f  (bu_cat+td_pad)
    float* overlay = acc + 6291456;                // 10,485,760 f (h | sim+cons)
    float* invn    = overlay + 10485760;           // 12,288 f
    __hip_bfloat16* lev_bf  = (__hip_bfloat16*)(invn + 12288);   // 6,291,456 bf16
    __hip_bfloat16* lp_bf   = lev_bf + 6291456;                  // 5,242,880
    __hip_bfloat16* wtin_bu = lp_bf + 5242880;                   // 5,242,880
    __hip_bfloat16* wtout_bu= wtin_bu + 5242880;                 // 5,242,880
    __hip_bfloat16* wtin_td = wtout_bu + 5242880;                // 5,242,880
    __hip_bfloat16* wtout_td= wtin_td + 5242880;                 // 5,242,880

    __hip_bfloat16* h = (__hip_bfloat16*)overlay;  // [5][2048][2048] bf16
    float* sim  = overlay;                         // [48][256][256] f (after FF)
    float* cons = overlay + 3145728;               // [2048][6][512] f

    init_levels_kernel<<<6144, 256, 0, stream>>>(levels, initlv);
    lev_lp_init<<<6144, 256, 0, stream>>>(levels, pos, lev_bf, lp_bf);
    patch_embed<<<NT_, 256, 0, stream>>>(img, Wp, bp, tokens);
    // weights: (5,512,2048)->(5,2048,512) and (5,2048,512)->(5,512,2048), bf16
    transpose_to_bf16<<<dim3(64, 16, 5), 256, 0, stream>>>(bu_in,  wtin_bu,  512, 2048);
    transpose_to_bf16<<<dim3(16, 64, 5), 256, 0, stream>>>(bu_out, wtout_bu, 2048, 512);
    transpose_to_bf16<<<dim3(64, 16, 5), 256, 0, stream>>>(td_in,  wtin_td,  512, 2048);
    transpose_to_bf16<<<dim3(16, 64, 5), 256, 0, stream>>>(td_out, wtout_td, 2048, 512);

    for (int it = 0; it < 12; ++it) {
        // FF1-bu: h[z] = gelu(lev[:,z,:] @ w)   M=2048 N=2048 K=512
        gemm_mfma<__hip_bfloat16, true, false><<<dim3(16, 16, 5), 256, 0, stream>>>(
            lev_bf, L_ * D_, 512,
            wtin_bu, D_, (long)HID_ * D_,
            h, HID_, (long)NT_ * HID_, D_);
        // FF2-bu: acc[:, z+1] = h[z] @ w2       M=2048 N=512 K=2048
        gemm_mfma<float, false, false><<<dim3(4, 16, 5), 256, 0, stream>>>(
            h, HID_, (long)NT_ * HID_,
            wtout_bu, HID_, (long)D_ * HID_,
            acc + D_, L_ * D_, D_, HID_);
        zero_l0<<<1024, 256, 0, stream>>>(acc);
        // FF1-td: h[z] = gelu((lev[:,z+1,:]+pos) @ w)
        gemm_mfma<__hip_bfloat16, true, false><<<dim3(16, 16, 5), 256, 0, stream>>>(
            lp_bf, 5 * D_, 512,
            wtin_td, D_, (long)HID_ * D_,
            h, HID_, (long)NT_ * HID_, D_);
        // FF2-td: acc[:, z] += h[z] @ w2
        gemm_mfma<float, false, true><<<dim3(4, 16, 5), 256, 0, stream>>>(
            h, HID_, (long)NT_ * HID_,
            wtout_td, HID_, (long)D_ * HID_,
            acc, L_ * D_, D_, HID_);

        invnorm_kernel<<<3072, 256, 0, stream>>>(levels, invn);
        sim_kernel<<<dim3(4, 4, 48), 256, 0, stream>>>(levels, invn, sim);
        softmax_kernel<<<3072, 256, 0, stream>>>(sim);
        gemm_nn<<<dim3(8, 4, 48), 256, 0, stream>>>(
            sim, N_, (long)N_ * N_,
            levels, L_ * D_, (long)N_ * L_ * D_, D_,
            cons, L_ * D_, (long)N_ * L_ * D_, D_, 6, N_);
        update_kernel<<<6144, 256, 0, stream>>>(levels, tokens, acc, cons, pos,
                                                lev_bf, lp_bf);
    }
}

// Round 3
// 3457.567 us; speedup vs baseline: 6.5514x; 1.2180x over previous
//
#include <hip/hip_runtime.h>
#include <hip/hip_bf16.h>
#include <math.h>

#define B_   8
#define N_   256
#define L_   6
#define D_   512
#define NT_  2048   // B_*N_
#define HID_ 2048

typedef __attribute__((ext_vector_type(4))) float f32x4;
typedef __attribute__((ext_vector_type(8))) short bf16x8;

struct bf16x4s { __hip_bfloat16 x, y, z, w; };

__device__ __forceinline__ bf16x4s to_bf4(float a, float b, float c, float d) {
    bf16x4s r;
    r.x = __float2bfloat16(a); r.y = __float2bfloat16(b);
    r.z = __float2bfloat16(c); r.w = __float2bfloat16(d);
    return r;
}

__device__ __forceinline__ void gload16(const void* g, void* l) {
    __builtin_amdgcn_global_load_lds(
        (const __attribute__((address_space(1))) int*)g,
        (__attribute__((address_space(3))) int*)l, 16, 0, 0);
}

// ---------------------------------------------------------------------------
// Shared MFMA tile K-loop: 128x128 tile, BK=32, 4 waves (2x2), 4x4 frags of
// 16x16x32_bf16. Both operands K-contiguous row-major. 16B-slot XOR swizzle
// (slot ^= (row>>1)&3) on BOTH global_load_lds source and ds_read (rule #21).
// ---------------------------------------------------------------------------
__device__ __forceinline__ void mfma_kloop(
    const __hip_bfloat16* __restrict__ A, int lda,
    const __hip_bfloat16* __restrict__ B, int ldb,
    int m0, int n0, int K, short* As, short* Bs,
    f32x4 acc[4][4], int wave, int lane)
{
    const int srow_in = lane >> 2;
    const int sslot   = lane & 3;
    const int wm = (wave >> 1) * 64, wn = (wave & 1) * 64;

    for (int k0 = 0; k0 < K; k0 += 32) {
        __syncthreads();
#pragma unroll
        for (int c = 0; c < 2; ++c) {
            const int rbase = c * 64 + wave * 16;      // wave-uniform
            const int row   = rbase + srow_in;
            const int gk    = sslot ^ ((row >> 1) & 3);
            gload16(A + (long)(m0 + row) * lda + k0 + gk * 8, As + rbase * 32);
            gload16(B + (long)(n0 + row) * ldb + k0 + gk * 8, Bs + rbase * 32);
        }
        __syncthreads();

        const int fr = lane & 15, ksub = lane >> 4;
        bf16x8 af[4], bfr[4];
#pragma unroll
        for (int i = 0; i < 4; ++i) {
            const int ra = wm + i * 16 + fr;
            af[i]  = *(const bf16x8*)(As + ra * 32 + (ksub ^ ((ra >> 1) & 3)) * 8);
            const int rb = wn + i * 16 + fr;
            bfr[i] = *(const bf16x8*)(Bs + rb * 32 + (ksub ^ ((rb >> 1) & 3)) * 8);
        }
#pragma unroll
        for (int i = 0; i < 4; ++i)
#pragma unroll
            for (int j = 0; j < 4; ++j)
                acc[i][j] = __builtin_amdgcn_mfma_f32_16x16x32_bf16(
                    af[i], bfr[j], acc[i][j], 0, 0, 0);
    }
}

// Generic: A (MxK), B (NxK, pre-transposed), C (MxN). Optional bias[n], GELU.
template<typename CT, bool GELU, bool ACCUM>
__global__ __launch_bounds__(256) void gemm_mfma(
    const __hip_bfloat16* __restrict__ A, int lda, long az,
    const __hip_bfloat16* __restrict__ B, int ldb, long bz,
    CT* __restrict__ C, int ldc, long cz, int K,
    const float* __restrict__ bias)
{
    __shared__ short As[128 * 32];
    __shared__ short Bs[128 * 32];
    const int tid = threadIdx.x;
    const int wave = tid >> 6, lane = tid & 63;
    const int z = blockIdx.z;
    A += (long)z * az;  B += (long)z * bz;  C += (long)z * cz;
    const int m0 = blockIdx.y * 128, n0 = blockIdx.x * 128;
    const int wm = (wave >> 1) * 64, wn = (wave & 1) * 64;

    f32x4 acc[4][4] = {};
    mfma_kloop(A, lda, B, ldb, m0, n0, K, As, Bs, acc, wave, lane);

    const int cr = lane >> 4, cc = lane & 15;
#pragma unroll
    for (int j = 0; j < 4; ++j) {
        const int col = n0 + wn + j * 16 + cc;
        const float bv = bias ? bias[col] : 0.f;
#pragma unroll
        for (int i = 0; i < 4; ++i)
#pragma unroll
            for (int r = 0; r < 4; ++r) {
                const int row = m0 + wm + i * 16 + cr * 4 + r;
                float v = acc[i][j][r] + bv;
                if (GELU) v = 0.5f * v * (1.0f + erff(v * 0.70710678118654752f));
                CT* p = &C[(long)row * ldc + col];
                if constexpr (ACCUM) *p = *p + (CT)v;
                else if constexpr (sizeof(CT) == 2) *p = __float2bfloat16(v);
                else *p = (CT)v;
            }
    }
}

// sim[z][i][j] = dot(lev[b,i,l,:], lev[b,j,l,:]) * invn_j / sqrt(512); diag=-5e-4
__global__ __launch_bounds__(256) void sim_mfma(
    const __hip_bfloat16* __restrict__ lev_bf, const float* __restrict__ invn,
    float* __restrict__ sim)
{
    __shared__ short As[128 * 32];
    __shared__ short Bs[128 * 32];
    const int tid = threadIdx.x;
    const int wave = tid >> 6, lane = tid & 63;
    const int z = blockIdx.z;
    const int b = z / 6, l = z - 6 * b;
    const __hip_bfloat16* base = lev_bf + (long)b * (N_ * L_ * D_) + (long)l * D_;
    const int m0 = blockIdx.y * 128, n0 = blockIdx.x * 128;
    const int wm = (wave >> 1) * 64, wn = (wave & 1) * 64;

    f32x4 acc[4][4] = {};
    mfma_kloop(base, L_ * D_, base, L_ * D_, m0, n0, D_, As, Bs, acc, wave, lane);

    const int cr = lane >> 4, cc = lane & 15;
    const float sc = 0.044194173824159216f;
#pragma unroll
    for (int j = 0; j < 4; ++j) {
        const int jg = n0 + wn + j * 16 + cc;
        const float iv = invn[((long)b * N_ + jg) * L_ + l] * sc;
#pragma unroll
        for (int i = 0; i < 4; ++i)
#pragma unroll
            for (int r = 0; r < 4; ++r) {
                const int ig = m0 + wm + i * 16 + cr * 4 + r;
                float v = acc[i][j][r] * iv;
                if (ig == jg) v = -0.0005f;
                sim[((long)z * N_ + ig) * N_ + jg] = v;
            }
    }
}

// cons[b, i, l, :] = attn[z] (256x256, bf16) @ levT[z] (512x256, bf16)^T
__global__ __launch_bounds__(256) void cons_mfma(
    const __hip_bfloat16* __restrict__ attn, const __hip_bfloat16* __restrict__ levT,
    float* __restrict__ cons)
{
    __shared__ short As[128 * 32];
    __shared__ short Bs[128 * 32];
    const int tid = threadIdx.x;
    const int wave = tid >> 6, lane = tid & 63;
    const int z = blockIdx.z;
    const int b = z / 6, l = z - 6 * b;
    const __hip_bfloat16* A = attn + (long)z * N_ * N_;
    const __hip_bfloat16* B = levT + (long)z * D_ * N_;
    float* C = cons + (long)b * (N_ * L_ * D_) + (long)l * D_;
    const int m0 = blockIdx.y * 128, n0 = blockIdx.x * 128;
    const int wm = (wave >> 1) * 64, wn = (wave & 1) * 64;

    f32x4 acc[4][4] = {};
    mfma_kloop(A, N_, B, N_, m0, n0, N_, As, Bs, acc, wave, lane);

    const int cr = lane >> 4, cc = lane & 15;
#pragma unroll
    for (int j = 0; j < 4; ++j) {
        const int col = n0 + wn + j * 16 + cc;
#pragma unroll
        for (int i = 0; i < 4; ++i)
#pragma unroll
            for (int r = 0; r < 4; ++r) {
                const int row = m0 + wm + i * 16 + cr * 4 + r;
                C[(long)row * (L_ * D_) + col] = acc[i][j][r];
            }
    }
}

// 32x32 LDS tile transpose, fp32 -> bf16:  dst[c][r] = src[r][c]
__global__ __launch_bounds__(256) void transpose_to_bf16(
    const float* __restrict__ src, __hip_bfloat16* __restrict__ dst,
    int R, int Cc)
{
    __shared__ float t[32][33];
    const int zz = blockIdx.z;
    src += (long)zz * R * Cc;  dst += (long)zz * R * Cc;
    const int tx = threadIdx.x & 31, ty = threadIdx.x >> 5;
    const int c0 = blockIdx.x * 32, r0 = blockIdx.y * 32;
#pragma unroll
    for (int i = 0; i < 4; ++i)
        t[ty + i * 8][tx] = src[(long)(r0 + ty + i * 8) * Cc + c0 + tx];
    __syncthreads();
#pragma unroll
    for (int i = 0; i < 4; ++i)
        dst[(long)(c0 + ty + i * 8) * R + r0 + tx] = __float2bfloat16(t[tx][ty + i * 8]);
}

// levels fp32 [t][l][d] -> levT bf16 [z=b*6+l][d][j]
__global__ __launch_bounds__(256) void levT_kernel(
    const float* __restrict__ levels, __hip_bfloat16* __restrict__ levT)
{
    __shared__ float t[32][33];
    const int z = blockIdx.z;
    const int b = z / 6, l = z - 6 * b;
    const float* base = levels + (long)b * (N_ * L_ * D_) + (long)l * D_;
    const int tx = threadIdx.x & 31, ty = threadIdx.x >> 5;
    const int d0 = blockIdx.x * 32, j0 = blockIdx.y * 32;
#pragma unroll
    for (int i = 0; i < 4; ++i)
        t[ty + i * 8][tx] = base[(long)(j0 + ty + i * 8) * (L_ * D_) + d0 + tx];
    __syncthreads();
#pragma unroll
    for (int i = 0; i < 4; ++i)
        levT[(long)z * D_ * N_ + (long)(d0 + ty + i * 8) * N_ + j0 + tx] =
            __float2bfloat16(t[tx][ty + i * 8]);
}

__global__ __launch_bounds__(256) void invnorm_kernel(
    const float* __restrict__ levels, float* __restrict__ invn)
{
    const int wid = blockIdx.x * 4 + (threadIdx.x >> 6);
    const int lane = threadIdx.x & 63;
    const float* row = levels + (long)wid * 512;
    float s = 0.f;
#pragma unroll
    for (int k = lane * 4; k < 512; k += 256) {
        const float4 v = *(const float4*)&row[k];
        s += v.x * v.x + v.y * v.y + v.z * v.z + v.w * v.w;
    }
#pragma unroll
    for (int o = 1; o < 64; o <<= 1) s += __shfl_xor(s, o);
    if (lane == 0) invn[wid] = 1.0f / fmaxf(sqrtf(s), 1e-12f);
}

// softmax over fp32 sim rows -> bf16 attn
__global__ __launch_bounds__(256) void softmax_kernel(
    const float* __restrict__ sim, __hip_bfloat16* __restrict__ attn)
{
    const long row = (long)blockIdx.x * 4 + (threadIdx.x >> 6);
    const int lane = threadIdx.x & 63;
    const float* p = sim + row * 256;
    float4 v = *(const float4*)&p[lane * 4];
    float m = fmaxf(fmaxf(v.x, v.y), fmaxf(v.z, v.w));
#pragma unroll
    for (int o = 1; o < 64; o <<= 1) m = fmaxf(m, __shfl_xor(m, o));
    v.x = expf(v.x - m); v.y = expf(v.y - m);
    v.z = expf(v.z - m); v.w = expf(v.w - m);
    float s = v.x + v.y + v.z + v.w;
#pragma unroll
    for (int o = 1; o < 64; o <<= 1) s += __shfl_xor(s, o);
    const float inv = 1.0f / s;
    *(bf16x4s*)&attn[row * 256 + lane * 4] =
        to_bf4(v.x * inv, v.y * inv, v.z * inv, v.w * inv);
}

// img -> patchified bf16 rows [2048][608] (K padded 588->608 with zeros)
__global__ __launch_bounds__(256) void patchify_kernel(
    const float* __restrict__ img, __hip_bfloat16* __restrict__ Xp)
{
    const int t = blockIdx.x;
    const int b = t >> 8, n = t & 255;
    const int hh = n >> 4, ww = n & 15;
    for (int k = threadIdx.x; k < 608; k += 256) {
        float v = 0.f;
        if (k < 588) {
            const int c = k % 3;
            const int pj = (k / 3) % 14;
            const int pi = k / 42;
            v = img[(((long)b * 3 + c) * 224 + (hh * 14 + pi)) * 224 + (ww * 14 + pj)];
        }
        Xp[(long)t * 608 + k] = __float2bfloat16(v);
    }
}

// Wp [588][512] fp32 -> WpT bf16 [512][608] (pad 0)
__global__ __launch_bounds__(256) void wpT_kernel(
    const float* __restrict__ Wp, __hip_bfloat16* __restrict__ WpT)
{
    __shared__ float t[32][33];
    const int k0 = blockIdx.x * 32, d0 = blockIdx.y * 32;
    const int tx = threadIdx.x & 31, ty = threadIdx.x >> 5;
#pragma unroll
    for (int i = 0; i < 4; ++i) {
        const int k = k0 + ty + i * 8;
        t[ty + i * 8][tx] = (k < 588) ? Wp[(long)k * 512 + d0 + tx] : 0.f;
    }
    __syncthreads();
#pragma unroll
    for (int i = 0; i < 4; ++i)
        WpT[(long)(d0 + ty + i * 8) * 608 + k0 + tx] = __float2bfloat16(t[tx][ty + i * 8]);
}

__global__ __launch_bounds__(256) void init_levels_kernel(
    float* __restrict__ levels, const float* __restrict__ initlv)
{
    const long f = (long)blockIdx.x * 256 + threadIdx.x;
    const int d4 = f & 127;
    const int l = (int)((f >> 7) % 6);
    *(float4*)&levels[f * 4] = *(const float4*)&initlv[(long)l * 512 + d4 * 4];
}

__global__ __launch_bounds__(256) void lev_lp_init(
    const float* __restrict__ levels, const float* __restrict__ pos,
    __hip_bfloat16* __restrict__ lev_bf, __hip_bfloat16* __restrict__ lp_bf)
{
    const long f = (long)blockIdx.x * 256 + threadIdx.x;
    const int d4 = f & 127;
    const long tl = f >> 7;
    const int l = (int)(tl % 6);
    const long t = tl / 6;
    const float4 v = *(const float4*)&levels[f * 4];
    *(bf16x4s*)&lev_bf[f * 4] = to_bf4(v.x, v.y, v.z, v.w);
    if (l >= 1) {
        const float4 p = *(const float4*)&pos[(long)(t & 255) * 512 + d4 * 4];
        *(bf16x4s*)&lp_bf[((t * 5 + l - 1) * 512) + d4 * 4] =
            to_bf4(v.x + p.x, v.y + p.y, v.z + p.z, v.w + p.w);
    }
}

__global__ __launch_bounds__(256) void zero_l0(float* __restrict__ acc)
{
    const long f = (long)blockIdx.x * 256 + threadIdx.x;   // 2048*128
    const long t = f >> 7;
    const int d4 = (int)(f & 127);
    *(float4*)&acc[t * 3072 + d4 * 4] = make_float4(0.f, 0.f, 0.f, 0.f);
}

__global__ __launch_bounds__(256) void update_kernel(
    float* __restrict__ levels, const float* __restrict__ tokens,
    const float* __restrict__ acc, const float* __restrict__ cons,
    const float* __restrict__ pos,
    __hip_bfloat16* __restrict__ lev_bf, __hip_bfloat16* __restrict__ lp_bf)
{
    const long f = (long)blockIdx.x * 256 + threadIdx.x;
    const int d4 = f & 127;
    const long tl = f >> 7;
    const int l = (int)(tl % 6);
    const long t = tl / 6;
    const long off = f * 4;

    float4 lev = *(float4*)&levels[off];
    const float4 cns = *(const float4*)&cons[off];
    float4 ac  = *(const float4*)&acc[off];
    if (l == 0) {
        const float4 bot = *(const float4*)&tokens[t * 512 + d4 * 4];
        ac.x += bot.x; ac.y += bot.y; ac.z += bot.z; ac.w += bot.w;
    }
    lev.x = (lev.x + ac.x + cns.x) * 0.25f;
    lev.y = (lev.y + ac.y + cns.y) * 0.25f;
    lev.z = (lev.z + ac.z + cns.z) * 0.25f;
    lev.w = (lev.w + ac.w + cns.w) * 0.25f;
    *(float4*)&levels[off] = lev;
    *(bf16x4s*)&lev_bf[off] = to_bf4(lev.x, lev.y, lev.z, lev.w);
    if (l >= 1) {
        const float4 p = *(const float4*)&pos[(long)(t & 255) * 512 + d4 * 4];
        *(bf16x4s*)&lp_bf[((t * 5 + l - 1) * 512) + d4 * 4] =
            to_bf4(lev.x + p.x, lev.y + p.y, lev.z + p.z, lev.w + p.w);
    }
}

extern "C" void kernel_launch(void* const* d_in, const int* in_sizes, int n_in,
                              void* d_out, int out_size, void* d_ws, size_t ws_size,
                              hipStream_t stream)
{
    const float* img    = (const float*)d_in[0];
    const float* Wp     = (const float*)d_in[1];
    const float* bp     = (const float*)d_in[2];
    const float* pos    = (const float*)d_in[3];
    const float* initlv = (const float*)d_in[4];
    const float* bu_in  = (const float*)d_in[5];
    const float* bu_out = (const float*)d_in[6];
    const float* td_in  = (const float*)d_in[7];
    const float* td_out = (const float*)d_in[8];

    float* levels = (float*)d_out;                 // [2048][6][512] fp32
    float* ws = (float*)d_ws;
    float* tokens  = ws;                           // 1,048,576 f
    float* acc     = tokens + 1048576;             // 6,291,456 f
    float* overlay = acc + 6291456;                // 10,485,760 f (h | sim+cons)
    float* invn    = overlay + 10485760;           // 12,288 f
    __hip_bfloat16* lev_bf  = (__hip_bfloat16*)(invn + 12288);   // 6,291,456 bf16
    __hip_bfloat16* lp_bf   = lev_bf + 6291456;                  // 5,242,880
    __hip_bfloat16* wtin_bu = lp_bf + 5242880;                   // 5,242,880
    __hip_bfloat16* wtout_bu= wtin_bu + 5242880;                 // 5,242,880
    __hip_bfloat16* wtin_td = wtout_bu + 5242880;                // 5,242,880
    __hip_bfloat16* wtout_td= wtin_td + 5242880;                 // 5,242,880

    __hip_bfloat16* h = (__hip_bfloat16*)overlay;  // [5][2048][2048] bf16
    float* sim  = overlay;                         // [48][256][256] f
    float* cons = overlay + 3145728;               // [2048][6][512] f
    // aliases (dead/rewritten regions — see liveness argument):
    __hip_bfloat16* levT_bf = lev_bf;              // [48][512][256] bf16
    __hip_bfloat16* attn_bf = lp_bf;               // [48][256][256] bf16
    __hip_bfloat16* Xp  = (__hip_bfloat16*)acc;    // [2048][608] (dead until FF2)
    __hip_bfloat16* WpT = Xp + 1245184;            // [512][608]

    init_levels_kernel<<<6144, 256, 0, stream>>>(levels, initlv);
    lev_lp_init<<<6144, 256, 0, stream>>>(levels, pos, lev_bf, lp_bf);
    // patch embed via MFMA
    patchify_kernel<<<NT_, 256, 0, stream>>>(img, Xp);
    wpT_kernel<<<dim3(19, 16), 256, 0, stream>>>(Wp, WpT);
    gemm_mfma<float, false, false><<<dim3(4, 16, 1), 256, 0, stream>>>(
        Xp, 608, 0, WpT, 608, 0, tokens, 512, 0, 608, bp);
    // weights: (5,512,2048)->(5,2048,512) and (5,2048,512)->(5,512,2048), bf16
    transpose_to_bf16<<<dim3(64, 16, 5), 256, 0, stream>>>(bu_in,  wtin_bu,  512, 2048);
    transpose_to_bf16<<<dim3(16, 64, 5), 256, 0, stream>>>(bu_out, wtout_bu, 2048, 512);
    transpose_to_bf16<<<dim3(64, 16, 5), 256, 0, stream>>>(td_in,  wtin_td,  512, 2048);
    transpose_to_bf16<<<dim3(16, 64, 5), 256, 0, stream>>>(td_out, wtout_td, 2048, 512);

    for (int it = 0; it < 12; ++it) {
        // FF1-bu: h[z] = gelu(lev[:,z,:] @ w)   M=2048 N=2048 K=512
        gemm_mfma<__hip_bfloat16, true, false><<<dim3(16, 16, 5), 256, 0, stream>>>(
            lev_bf, L_ * D_, 512,
            wtin_bu, D_, (long)HID_ * D_,
            h, HID_, (long)NT_ * HID_, D_, nullptr);
        // FF2-bu: acc[:, z+1] = h[z] @ w2       M=2048 N=512 K=2048
        gemm_mfma<float, false, false><<<dim3(4, 16, 5), 256, 0, stream>>>(
            h, HID_, (long)NT_ * HID_,
            wtout_bu, HID_, (long)D_ * HID_,
            acc + D_, L_ * D_, D_, HID_, nullptr);
        zero_l0<<<1024, 256, 0, stream>>>(acc);
        // FF1-td: h[z] = gelu((lev[:,z+1,:]+pos) @ w)
        gemm_mfma<__hip_bfloat16, true, false><<<dim3(16, 16, 5), 256, 0, stream>>>(
            lp_bf, 5 * D_, 512,
            wtin_td, D_, (long)HID_ * D_,
            h, HID_, (long)NT_ * HID_, D_, nullptr);
        // FF2-td: acc[:, z] += h[z] @ w2
        gemm_mfma<float, false, true><<<dim3(4, 16, 5), 256, 0, stream>>>(
            h, HID_, (long)NT_ * HID_,
            wtout_td, HID_, (long)D_ * HID_,
            acc, L_ * D_, D_, HID_, nullptr);

        // consensus, all MFMA
        invnorm_kernel<<<3072, 256, 0, stream>>>(levels, invn);
        sim_mfma<<<dim3(2, 2, 48), 256, 0, stream>>>(lev_bf, invn, sim);
        softmax_kernel<<<3072, 256, 0, stream>>>(sim, attn_bf);   // lp_bf dead
        levT_kernel<<<dim3(16, 8, 48), 256, 0, stream>>>(levels, levT_bf); // lev_bf dead
        cons_mfma<<<dim3(4, 2, 48), 256, 0, stream>>>(attn_bf, levT_bf, cons);
        update_kernel<<<6144, 256, 0, stream>>>(levels, tokens, acc, cons, pos,
                                                lev_bf, lp_bf);
    }
}

// Round 4
// 3257.542 us; speedup vs baseline: 6.9537x; 1.0614x over previous
//
#include <hip/hip_runtime.h>
#include <hip/hip_bf16.h>
#include <math.h>

#define B_   8
#define N_   256
#define L_   6
#define D_   512
#define NT_  2048   // B_*N_
#define HID_ 2048

typedef __attribute__((ext_vector_type(4))) float f32x4;
typedef __attribute__((ext_vector_type(8))) short bf16x8;

struct bf16x4s { __hip_bfloat16 x, y, z, w; };

__device__ __forceinline__ bf16x4s to_bf4(float a, float b, float c, float d) {
    bf16x4s r;
    r.x = __float2bfloat16(a); r.y = __float2bfloat16(b);
    r.z = __float2bfloat16(c); r.w = __float2bfloat16(d);
    return r;
}

__device__ __forceinline__ void gload16(const void* g, void* l) {
    __builtin_amdgcn_global_load_lds(
        (const __attribute__((address_space(1))) int*)g,
        (__attribute__((address_space(3))) int*)l, 16, 0, 0);
}

// ---------------------------------------------------------------------------
// Big-tile FF GEMM: BM x BN tile, BK=64, 512 threads = 8 waves (WM x WN).
// Double-buffered LDS, ONE barrier per K-tile (prefetch overlaps compute).
// Both operands K-contiguous row-major (B pre-transposed: N x K).
// LDS rows = 64 bf16 = 8 x 16B slots; XOR swizzle slot ^= (row&7) applied on
// global source (pre-swizzle) and ds_read addr; gload_lds dest stays linear
// (rule #21c). XCD-aware bijective blockIdx swizzle (requires nwg % 8 == 0).
// ---------------------------------------------------------------------------
template<int BM, int BN, int WM, int WN, typename CT, bool GELU, bool ACCUM>
__global__ __launch_bounds__(512, 2) void gemm_ff(
    const __hip_bfloat16* __restrict__ A, int lda, long az,
    const __hip_bfloat16* __restrict__ B, int ldb, long bz,
    CT* __restrict__ C, int ldc, long cz, int K)
{
    constexpr int WVM = BM / WM, WVN = BN / WN;   // per-wave output
    constexpr int MR = WVM / 16, NR = WVN / 16;   // fragment repeats
    constexpr int ALOADS = (BM * 64) / (512 * 8); // 16B issues/thread for A
    constexpr int BLOADS = (BN * 64) / (512 * 8);

    __shared__ short As[2][BM * 64];
    __shared__ short Bs[2][BN * 64];

    const int tid = threadIdx.x;
    const int wv = tid >> 6, lane = tid & 63;
    const int wr = wv / WN, wc = wv % WN;

    // XCD-aware bijective swizzle over the linear block id
    const int gx = gridDim.x, gy = gridDim.y;
    const int nwg = gx * gy * gridDim.z;
    int lid = (blockIdx.z * gy + blockIdx.y) * gx + blockIdx.x;
    lid = (lid & 7) * (nwg >> 3) + (lid >> 3);
    const int bx = lid % gx, by = (lid / gx) % gy, bzz = lid / (gx * gy);

    A += (long)bzz * az;  B += (long)bzz * bz;  C += (long)bzz * cz;
    const int m0 = by * BM, n0 = bx * BN;

    f32x4 acc[MR][NR] = {};

    const int srow_a = tid >> 3, sslot = tid & 7;   // for staging addr calc

#define STAGE(BUF, K0)                                                        \
    {                                                                         \
        _Pragma("unroll")                                                     \
        for (int i = 0; i < ALOADS; ++i) {                                    \
            const int row = srow_a + i * 64;                                  \
            const int gs  = sslot ^ (row & 7);                                \
            gload16(A + (long)(m0 + row) * lda + (K0) + gs * 8,               \
                    &As[BUF][(wv * 64 + i * 512) * 8]);                       \
        }                                                                     \
        _Pragma("unroll")                                                     \
        for (int i = 0; i < BLOADS; ++i) {                                    \
            const int row = srow_a + i * 64;                                  \
            const int gs  = sslot ^ (row & 7);                                \
            gload16(B + (long)(n0 + row) * ldb + (K0) + gs * 8,               \
                    &Bs[BUF][(wv * 64 + i * 512) * 8]);                       \
        }                                                                     \
    }

    const int fr = lane & 15, k4 = lane >> 4;
    const int nt = K / 64;
    int cur = 0;

    STAGE(0, 0);
    __syncthreads();

    for (int t = 0; t < nt; ++t) {
        if (t + 1 < nt) STAGE(cur ^ 1, (t + 1) * 64);
#pragma unroll
        for (int ks = 0; ks < 2; ++ks) {
            bf16x8 af[MR], bf[NR];
#pragma unroll
            for (int i = 0; i < MR; ++i) {
                const int r = wr * WVM + i * 16 + fr;
                af[i] = *(const bf16x8*)&As[cur][r * 64 + ((ks * 4 + k4) ^ (r & 7)) * 8];
            }
#pragma unroll
            for (int j = 0; j < NR; ++j) {
                const int r = wc * WVN + j * 16 + fr;
                bf[j] = *(const bf16x8*)&Bs[cur][r * 64 + ((ks * 4 + k4) ^ (r & 7)) * 8];
            }
#pragma unroll
            for (int i = 0; i < MR; ++i)
#pragma unroll
                for (int j = 0; j < NR; ++j)
                    acc[i][j] = __builtin_amdgcn_mfma_f32_16x16x32_bf16(
                        af[i], bf[j], acc[i][j], 0, 0, 0);
        }
        __syncthreads();   // drains stage vmcnt + all lds reads of cur
        cur ^= 1;
    }
#undef STAGE

    const int cr4 = (lane >> 4) * 4, cc = lane & 15;
#pragma unroll
    for (int i = 0; i < MR; ++i)
#pragma unroll
        for (int j = 0; j < NR; ++j) {
            const int col = n0 + wc * WVN + j * 16 + cc;
#pragma unroll
            for (int r = 0; r < 4; ++r) {
                const int row = m0 + wr * WVM + i * 16 + cr4 + r;
                float v = acc[i][j][r];
                if (GELU) v = 0.5f * v * (1.0f + erff(v * 0.70710678118654752f));
                CT* p = &C[(long)row * ldc + col];
                if constexpr (ACCUM) *p = *p + (CT)v;
                else if constexpr (sizeof(CT) == 2) *p = __float2bfloat16(v);
                else *p = (CT)v;
            }
        }
}

// ---------------------------------------------------------------------------
// 128^2 MFMA kernels (patch embed, sim, cons) — verified round-3 versions
// ---------------------------------------------------------------------------
__device__ __forceinline__ void mfma_kloop(
    const __hip_bfloat16* __restrict__ A, int lda,
    const __hip_bfloat16* __restrict__ B, int ldb,
    int m0, int n0, int K, short* As, short* Bs,
    f32x4 acc[4][4], int wave, int lane)
{
    const int srow_in = lane >> 2;
    const int sslot   = lane & 3;
    const int wm = (wave >> 1) * 64, wn = (wave & 1) * 64;

    for (int k0 = 0; k0 < K; k0 += 32) {
        __syncthreads();
#pragma unroll
        for (int c = 0; c < 2; ++c) {
            const int rbase = c * 64 + wave * 16;
            const int row   = rbase + srow_in;
            const int gk    = sslot ^ ((row >> 1) & 3);
            gload16(A + (long)(m0 + row) * lda + k0 + gk * 8, As + rbase * 32);
            gload16(B + (long)(n0 + row) * ldb + k0 + gk * 8, Bs + rbase * 32);
        }
        __syncthreads();

        const int fr = lane & 15, ksub = lane >> 4;
        bf16x8 af[4], bfr[4];
#pragma unroll
        for (int i = 0; i < 4; ++i) {
            const int ra = wm + i * 16 + fr;
            af[i]  = *(const bf16x8*)(As + ra * 32 + (ksub ^ ((ra >> 1) & 3)) * 8);
            const int rb = wn + i * 16 + fr;
            bfr[i] = *(const bf16x8*)(Bs + rb * 32 + (ksub ^ ((rb >> 1) & 3)) * 8);
        }
#pragma unroll
        for (int i = 0; i < 4; ++i)
#pragma unroll
            for (int j = 0; j < 4; ++j)
                acc[i][j] = __builtin_amdgcn_mfma_f32_16x16x32_bf16(
                    af[i], bfr[j], acc[i][j], 0, 0, 0);
    }
}

template<typename CT, bool GELU, bool ACCUM>
__global__ __launch_bounds__(256) void gemm_mfma(
    const __hip_bfloat16* __restrict__ A, int lda, long az,
    const __hip_bfloat16* __restrict__ B, int ldb, long bz,
    CT* __restrict__ C, int ldc, long cz, int K,
    const float* __restrict__ bias)
{
    __shared__ short As[128 * 32];
    __shared__ short Bs[128 * 32];
    const int tid = threadIdx.x;
    const int wave = tid >> 6, lane = tid & 63;
    const int z = blockIdx.z;
    A += (long)z * az;  B += (long)z * bz;  C += (long)z * cz;
    const int m0 = blockIdx.y * 128, n0 = blockIdx.x * 128;
    const int wm = (wave >> 1) * 64, wn = (wave & 1) * 64;

    f32x4 acc[4][4] = {};
    mfma_kloop(A, lda, B, ldb, m0, n0, K, As, Bs, acc, wave, lane);

    const int cr = lane >> 4, cc = lane & 15;
#pragma unroll
    for (int j = 0; j < 4; ++j) {
        const int col = n0 + wn + j * 16 + cc;
        const float bv = bias ? bias[col] : 0.f;
#pragma unroll
        for (int i = 0; i < 4; ++i)
#pragma unroll
            for (int r = 0; r < 4; ++r) {
                const int row = m0 + wm + i * 16 + cr * 4 + r;
                float v = acc[i][j][r] + bv;
                if (GELU) v = 0.5f * v * (1.0f + erff(v * 0.70710678118654752f));
                CT* p = &C[(long)row * ldc + col];
                if constexpr (ACCUM) *p = *p + (CT)v;
                else if constexpr (sizeof(CT) == 2) *p = __float2bfloat16(v);
                else *p = (CT)v;
            }
    }
}

__global__ __launch_bounds__(256) void sim_mfma(
    const __hip_bfloat16* __restrict__ lev_bf, const float* __restrict__ invn,
    float* __restrict__ sim)
{
    __shared__ short As[128 * 32];
    __shared__ short Bs[128 * 32];
    const int tid = threadIdx.x;
    const int wave = tid >> 6, lane = tid & 63;
    const int z = blockIdx.z;
    const int b = z / 6, l = z - 6 * b;
    const __hip_bfloat16* base = lev_bf + (long)b * (N_ * L_ * D_) + (long)l * D_;
    const int m0 = blockIdx.y * 128, n0 = blockIdx.x * 128;
    const int wm = (wave >> 1) * 64, wn = (wave & 1) * 64;

    f32x4 acc[4][4] = {};
    mfma_kloop(base, L_ * D_, base, L_ * D_, m0, n0, D_, As, Bs, acc, wave, lane);

    const int cr = lane >> 4, cc = lane & 15;
    const float sc = 0.044194173824159216f;
#pragma unroll
    for (int j = 0; j < 4; ++j) {
        const int jg = n0 + wn + j * 16 + cc;
        const float iv = invn[((long)b * N_ + jg) * L_ + l] * sc;
#pragma unroll
        for (int i = 0; i < 4; ++i)
#pragma unroll
            for (int r = 0; r < 4; ++r) {
                const int ig = m0 + wm + i * 16 + cr * 4 + r;
                float v = acc[i][j][r] * iv;
                if (ig == jg) v = -0.0005f;
                sim[((long)z * N_ + ig) * N_ + jg] = v;
            }
    }
}

__global__ __launch_bounds__(256) void cons_mfma(
    const __hip_bfloat16* __restrict__ attn, const __hip_bfloat16* __restrict__ levT,
    float* __restrict__ cons)
{
    __shared__ short As[128 * 32];
    __shared__ short Bs[128 * 32];
    const int tid = threadIdx.x;
    const int wave = tid >> 6, lane = tid & 63;
    const int z = blockIdx.z;
    const int b = z / 6, l = z - 6 * b;
    const __hip_bfloat16* A = attn + (long)z * N_ * N_;
    const __hip_bfloat16* B = levT + (long)z * D_ * N_;
    float* C = cons + (long)b * (N_ * L_ * D_) + (long)l * D_;
    const int m0 = blockIdx.y * 128, n0 = blockIdx.x * 128;
    const int wm = (wave >> 1) * 64, wn = (wave & 1) * 64;

    f32x4 acc[4][4] = {};
    mfma_kloop(A, N_, B, N_, m0, n0, N_, As, Bs, acc, wave, lane);

    const int cr = lane >> 4, cc = lane & 15;
#pragma unroll
    for (int j = 0; j < 4; ++j) {
        const int col = n0 + wn + j * 16 + cc;
#pragma unroll
        for (int i = 0; i < 4; ++i)
#pragma unroll
            for (int r = 0; r < 4; ++r) {
                const int row = m0 + wm + i * 16 + cr * 4 + r;
                C[(long)row * (L_ * D_) + col] = acc[i][j][r];
            }
    }
}

// ---------------------------------------------------------------------------
// helper / elementwise kernels (verified)
// ---------------------------------------------------------------------------
__global__ __launch_bounds__(256) void transpose_to_bf16(
    const float* __restrict__ src, __hip_bfloat16* __restrict__ dst,
    int R, int Cc)
{
    __shared__ float t[32][33];
    const int zz = blockIdx.z;
    src += (long)zz * R * Cc;  dst += (long)zz * R * Cc;
    const int tx = threadIdx.x & 31, ty = threadIdx.x >> 5;
    const int c0 = blockIdx.x * 32, r0 = blockIdx.y * 32;
#pragma unroll
    for (int i = 0; i < 4; ++i)
        t[ty + i * 8][tx] = src[(long)(r0 + ty + i * 8) * Cc + c0 + tx];
    __syncthreads();
#pragma unroll
    for (int i = 0; i < 4; ++i)
        dst[(long)(c0 + ty + i * 8) * R + r0 + tx] = __float2bfloat16(t[tx][ty + i * 8]);
}

__global__ __launch_bounds__(256) void levT_kernel(
    const float* __restrict__ levels, __hip_bfloat16* __restrict__ levT)
{
    __shared__ float t[32][33];
    const int z = blockIdx.z;
    const int b = z / 6, l = z - 6 * b;
    const float* base = levels + (long)b * (N_ * L_ * D_) + (long)l * D_;
    const int tx = threadIdx.x & 31, ty = threadIdx.x >> 5;
    const int d0 = blockIdx.x * 32, j0 = blockIdx.y * 32;
#pragma unroll
    for (int i = 0; i < 4; ++i)
        t[ty + i * 8][tx] = base[(long)(j0 + ty + i * 8) * (L_ * D_) + d0 + tx];
    __syncthreads();
#pragma unroll
    for (int i = 0; i < 4; ++i)
        levT[(long)z * D_ * N_ + (long)(d0 + ty + i * 8) * N_ + j0 + tx] =
            __float2bfloat16(t[tx][ty + i * 8]);
}

__global__ __launch_bounds__(256) void invnorm_kernel(
    const float* __restrict__ levels, float* __restrict__ invn)
{
    const int wid = blockIdx.x * 4 + (threadIdx.x >> 6);
    const int lane = threadIdx.x & 63;
    const float* row = levels + (long)wid * 512;
    float s = 0.f;
#pragma unroll
    for (int k = lane * 4; k < 512; k += 256) {
        const float4 v = *(const float4*)&row[k];
        s += v.x * v.x + v.y * v.y + v.z * v.z + v.w * v.w;
    }
#pragma unroll
    for (int o = 1; o < 64; o <<= 1) s += __shfl_xor(s, o);
    if (lane == 0) invn[wid] = 1.0f / fmaxf(sqrtf(s), 1e-12f);
}

__global__ __launch_bounds__(256) void softmax_kernel(
    const float* __restrict__ sim, __hip_bfloat16* __restrict__ attn)
{
    const long row = (long)blockIdx.x * 4 + (threadIdx.x >> 6);
    const int lane = threadIdx.x & 63;
    const float* p = sim + row * 256;
    float4 v = *(const float4*)&p[lane * 4];
    float m = fmaxf(fmaxf(v.x, v.y), fmaxf(v.z, v.w));
#pragma unroll
    for (int o = 1; o < 64; o <<= 1) m = fmaxf(m, __shfl_xor(m, o));
    v.x = expf(v.x - m); v.y = expf(v.y - m);
    v.z = expf(v.z - m); v.w = expf(v.w - m);
    float s = v.x + v.y + v.z + v.w;
#pragma unroll
    for (int o = 1; o < 64; o <<= 1) s += __shfl_xor(s, o);
    const float inv = 1.0f / s;
    *(bf16x4s*)&attn[row * 256 + lane * 4] =
        to_bf4(v.x * inv, v.y * inv, v.z * inv, v.w * inv);
}

__global__ __launch_bounds__(256) void patchify_kernel(
    const float* __restrict__ img, __hip_bfloat16* __restrict__ Xp)
{
    const int t = blockIdx.x;
    const int b = t >> 8, n = t & 255;
    const int hh = n >> 4, ww = n & 15;
    for (int k = threadIdx.x; k < 608; k += 256) {
        float v = 0.f;
        if (k < 588) {
            const int c = k % 3;
            const int pj = (k / 3) % 14;
            const int pi = k / 42;
            v = img[(((long)b * 3 + c) * 224 + (hh * 14 + pi)) * 224 + (ww * 14 + pj)];
        }
        Xp[(long)t * 608 + k] = __float2bfloat16(v);
    }
}

__global__ __launch_bounds__(256) void wpT_kernel(
    const float* __restrict__ Wp, __hip_bfloat16* __restrict__ WpT)
{
    __shared__ float t[32][33];
    const int k0 = blockIdx.x * 32, d0 = blockIdx.y * 32;
    const int tx = threadIdx.x & 31, ty = threadIdx.x >> 5;
#pragma unroll
    for (int i = 0; i < 4; ++i) {
        const int k = k0 + ty + i * 8;
        t[ty + i * 8][tx] = (k < 588) ? Wp[(long)k * 512 + d0 + tx] : 0.f;
    }
    __syncthreads();
#pragma unroll
    for (int i = 0; i < 4; ++i)
        WpT[(long)(d0 + ty + i * 8) * 608 + k0 + tx] = __float2bfloat16(t[tx][ty + i * 8]);
}

__global__ __launch_bounds__(256) void init_levels_kernel(
    float* __restrict__ levels, const float* __restrict__ initlv)
{
    const long f = (long)blockIdx.x * 256 + threadIdx.x;
    const int d4 = f & 127;
    const int l = (int)((f >> 7) % 6);
    *(float4*)&levels[f * 4] = *(const float4*)&initlv[(long)l * 512 + d4 * 4];
}

__global__ __launch_bounds__(256) void lev_lp_init(
    const float* __restrict__ levels, const float* __restrict__ pos,
    __hip_bfloat16* __restrict__ lev_bf, __hip_bfloat16* __restrict__ lp_bf)
{
    const long f = (long)blockIdx.x * 256 + threadIdx.x;
    const int d4 = f & 127;
    const long tl = f >> 7;
    const int l = (int)(tl % 6);
    const long t = tl / 6;
    const float4 v = *(const float4*)&levels[f * 4];
    *(bf16x4s*)&lev_bf[f * 4] = to_bf4(v.x, v.y, v.z, v.w);
    if (l >= 1) {
        const float4 p = *(const float4*)&pos[(long)(t & 255) * 512 + d4 * 4];
        *(bf16x4s*)&lp_bf[((t * 5 + l - 1) * 512) + d4 * 4] =
            to_bf4(v.x + p.x, v.y + p.y, v.z + p.z, v.w + p.w);
    }
}

__global__ __launch_bounds__(256) void zero_l0(float* __restrict__ acc)
{
    const long f = (long)blockIdx.x * 256 + threadIdx.x;
    const long t = f >> 7;
    const int d4 = (int)(f & 127);
    *(float4*)&acc[t * 3072 + d4 * 4] = make_float4(0.f, 0.f, 0.f, 0.f);
}

__global__ __launch_bounds__(256) void update_kernel(
    float* __restrict__ levels, const float* __restrict__ tokens,
    const float* __restrict__ acc, const float* __restrict__ cons,
    const float* __restrict__ pos,
    __hip_bfloat16* __restrict__ lev_bf, __hip_bfloat16* __restrict__ lp_bf)
{
    const long f = (long)blockIdx.x * 256 + threadIdx.x;
    const int d4 = f & 127;
    const long tl = f >> 7;
    const int l = (int)(tl % 6);
    const long t = tl / 6;
    const long off = f * 4;

    float4 lev = *(float4*)&levels[off];
    const float4 cns = *(const float4*)&cons[off];
    float4 ac  = *(const float4*)&acc[off];
    if (l == 0) {
        const float4 bot = *(const float4*)&tokens[t * 512 + d4 * 4];
        ac.x += bot.x; ac.y += bot.y; ac.z += bot.z; ac.w += bot.w;
    }
    lev.x = (lev.x + ac.x + cns.x) * 0.25f;
    lev.y = (lev.y + ac.y + cns.y) * 0.25f;
    lev.z = (lev.z + ac.z + cns.z) * 0.25f;
    lev.w = (lev.w + ac.w + cns.w) * 0.25f;
    *(float4*)&levels[off] = lev;
    *(bf16x4s*)&lev_bf[off] = to_bf4(lev.x, lev.y, lev.z, lev.w);
    if (l >= 1) {
        const float4 p = *(const float4*)&pos[(long)(t & 255) * 512 + d4 * 4];
        *(bf16x4s*)&lp_bf[((t * 5 + l - 1) * 512) + d4 * 4] =
            to_bf4(lev.x + p.x, lev.y + p.y, lev.z + p.z, lev.w + p.w);
    }
}

extern "C" void kernel_launch(void* const* d_in, const int* in_sizes, int n_in,
                              void* d_out, int out_size, void* d_ws, size_t ws_size,
                              hipStream_t stream)
{
    const float* img    = (const float*)d_in[0];
    const float* Wp     = (const float*)d_in[1];
    const float* bp     = (const float*)d_in[2];
    const float* pos    = (const float*)d_in[3];
    const float* initlv = (const float*)d_in[4];
    const float* bu_in  = (const float*)d_in[5];
    const float* bu_out = (const float*)d_in[6];
    const float* td_in  = (const float*)d_in[7];
    const float* td_out = (const float*)d_in[8];

    float* levels = (float*)d_out;                 // [2048][6][512] fp32
    float* ws = (float*)d_ws;
    float* tokens  = ws;                           // 1,048,576 f
    float* acc     = tokens + 1048576;             // 6,291,456 f
    float* overlay = acc + 6291456;                // 10,485,760 f (h | sim+cons)
    float* invn    = overlay + 10485760;           // 12,288 f
    __hip_bfloat16* lev_bf  = (__hip_bfloat16*)(invn + 12288);   // 6,291,456 bf16
    __hip_bfloat16* lp_bf   = lev_bf + 6291456;                  // 5,242,880
    __hip_bfloat16* wtin_bu = lp_bf + 5242880;                   // 5,242,880
    __hip_bfloat16* wtout_bu= wtin_bu + 5242880;                 // 5,242,880
    __hip_bfloat16* wtin_td = wtout_bu + 5242880;                // 5,242,880
    __hip_bfloat16* wtout_td= wtin_td + 5242880;                 // 5,242,880

    __hip_bfloat16* h = (__hip_bfloat16*)overlay;  // [5][2048][2048] bf16
    float* sim  = overlay;                         // [48][256][256] f
    float* cons = overlay + 3145728;               // [2048][6][512] f
    __hip_bfloat16* levT_bf = lev_bf;              // [48][512][256] (alias)
    __hip_bfloat16* attn_bf = lp_bf;               // [48][256][256] (alias)
    __hip_bfloat16* Xp  = (__hip_bfloat16*)acc;    // [2048][608] (dead until FF2)
    __hip_bfloat16* WpT = Xp + 1245184;            // [512][608]

    init_levels_kernel<<<6144, 256, 0, stream>>>(levels, initlv);
    lev_lp_init<<<6144, 256, 0, stream>>>(levels, pos, lev_bf, lp_bf);
    patchify_kernel<<<NT_, 256, 0, stream>>>(img, Xp);
    wpT_kernel<<<dim3(19, 16), 256, 0, stream>>>(Wp, WpT);
    gemm_mfma<float, false, false><<<dim3(4, 16, 1), 256, 0, stream>>>(
        Xp, 608, 0, WpT, 608, 0, tokens, 512, 0, 608, bp);
    transpose_to_bf16<<<dim3(64, 16, 5), 256, 0, stream>>>(bu_in,  wtin_bu,  512, 2048);
    transpose_to_bf16<<<dim3(16, 64, 5), 256, 0, stream>>>(bu_out, wtout_bu, 2048, 512);
    transpose_to_bf16<<<dim3(64, 16, 5), 256, 0, stream>>>(td_in,  wtin_td,  512, 2048);
    transpose_to_bf16<<<dim3(16, 64, 5), 256, 0, stream>>>(td_out, wtout_td, 2048, 512);

    for (int it = 0; it < 12; ++it) {
        // FF1-bu: h[z] = gelu(lev[:,z,:] @ w)    M=2048 N=2048 K=512
        gemm_ff<256, 256, 2, 4, __hip_bfloat16, true, false>
            <<<dim3(8, 8, 5), 512, 0, stream>>>(
            lev_bf, L_ * D_, 512,
            wtin_bu, D_, (long)HID_ * D_,
            h, HID_, (long)NT_ * HID_, D_);
        // FF2-bu: acc[:, z+1] = h[z] @ w2        M=2048 N=512 K=2048
        gemm_ff<256, 128, 4, 2, float, false, false>
            <<<dim3(4, 8, 5), 512, 0, stream>>>(
            h, HID_, (long)NT_ * HID_,
            wtout_bu, HID_, (long)D_ * HID_,
            acc + D_, L_ * D_, D_, HID_);
        zero_l0<<<1024, 256, 0, stream>>>(acc);
        // FF1-td: h[z] = gelu((lev[:,z+1,:]+pos) @ w)
        gemm_ff<256, 256, 2, 4, __hip_bfloat16, true, false>
            <<<dim3(8, 8, 5), 512, 0, stream>>>(
            lp_bf, 5 * D_, 512,
            wtin_td, D_, (long)HID_ * D_,
            h, HID_, (long)NT_ * HID_, D_);
        // FF2-td: acc[:, z] += h[z] @ w2
        gemm_ff<256, 128, 4, 2, float, false, true>
            <<<dim3(4, 8, 5), 512, 0, stream>>>(
            h, HID_, (long)NT_ * HID_,
            wtout_td, HID_, (long)D_ * HID_,
            acc, L_ * D_, D_, HID_);

        invnorm_kernel<<<3072, 256, 0, stream>>>(levels, invn);
        sim_mfma<<<dim3(2, 2, 48), 256, 0, stream>>>(lev_bf, invn, sim);
        softmax_kernel<<<3072, 256, 0, stream>>>(sim, attn_bf);
        levT_kernel<<<dim3(16, 8, 48), 256, 0, stream>>>(levels, levT_bf);
        cons_mfma<<<dim3(4, 2, 48), 256, 0, stream>>>(attn_bf, levT_bf, cons);
        update_kernel<<<6144, 256, 0, stream>>>(levels, tokens, acc, cons, pos,
                                                lev_bf, lp_bf);
    }
}

// Round 5
// 2568.836 us; speedup vs baseline: 8.8180x; 1.2681x over previous
//
#include <hip/hip_runtime.h>
#include <hip/hip_bf16.h>
#include <math.h>

#define B_   8
#define N_   256
#define L_   6
#define D_   512
#define NT_  2048   // B_*N_
#define HID_ 2048

typedef __attribute__((ext_vector_type(4))) float f32x4;
typedef __attribute__((ext_vector_type(8))) short bf16x8;

struct bf16x4s { __hip_bfloat16 x, y, z, w; };

__device__ __forceinline__ bf16x4s to_bf4(float a, float b, float c, float d) {
    bf16x4s r;
    r.x = __float2bfloat16(a); r.y = __float2bfloat16(b);
    r.z = __float2bfloat16(c); r.w = __float2bfloat16(d);
    return r;
}

__device__ __forceinline__ void gload16(const void* g, void* l) {
    __builtin_amdgcn_global_load_lds(
        (const __attribute__((address_space(1))) int*)g,
        (__attribute__((address_space(3))) int*)l, 16, 0, 0);
}

// ---------------------------------------------------------------------------
// FF GEMM: BM x BN tile, BK=64, 512 threads = 8 waves (WM x WN).
// Double-buffered LDS, ONE barrier per K-tile. 128x128 -> LDS 64 KB ->
// 2 blocks/CU so the barrier drain overlaps with the co-resident block.
// B pre-transposed (N x K). XOR swizzle slot ^= (row&7) on pre-swizzled
// global source + ds_read addr (rule #21c); gload_lds dest linear.
// XCD-aware bijective blockIdx swizzle (nwg % 8 == 0).
// ---------------------------------------------------------------------------
template<int BM, int BN, int WM, int WN, typename CT, bool GELU, bool ACCUM>
__global__ __launch_bounds__(512, 4) void gemm_ff(
    const __hip_bfloat16* __restrict__ A, int lda, long az,
    const __hip_bfloat16* __restrict__ B, int ldb, long bz,
    CT* __restrict__ C, int ldc, long cz, int K)
{
    constexpr int WVM = BM / WM, WVN = BN / WN;   // per-wave output
    constexpr int MR = WVM / 16, NR = WVN / 16;   // fragment repeats
    constexpr int ALOADS = (BM * 64) / (512 * 8);
    constexpr int BLOADS = (BN * 64) / (512 * 8);

    __shared__ short As[2][BM * 64];
    __shared__ short Bs[2][BN * 64];

    const int tid = threadIdx.x;
    const int wv = tid >> 6, lane = tid & 63;
    const int wr = wv / WN, wc = wv % WN;

    // XCD-aware bijective swizzle over the linear block id
    const int gx = gridDim.x, gy = gridDim.y;
    const int nwg = gx * gy * gridDim.z;
    int lid = (blockIdx.z * gy + blockIdx.y) * gx + blockIdx.x;
    lid = (lid & 7) * (nwg >> 3) + (lid >> 3);
    const int bx = lid % gx, by = (lid / gx) % gy, bzz = lid / (gx * gy);

    A += (long)bzz * az;  B += (long)bzz * bz;  C += (long)bzz * cz;
    const int m0 = by * BM, n0 = bx * BN;

    f32x4 acc[MR][NR] = {};

    const int srow_a = tid >> 3, sslot = tid & 7;

#define STAGE(BUF, K0)                                                        \
    {                                                                         \
        _Pragma("unroll")                                                     \
        for (int i = 0; i < ALOADS; ++i) {                                    \
            const int row = srow_a + i * 64;                                  \
            const int gs  = sslot ^ (row & 7);                                \
            gload16(A + (long)(m0 + row) * lda + (K0) + gs * 8,               \
                    &As[BUF][(wv * 64 + i * 512) * 8]);                       \
        }                                                                     \
        _Pragma("unroll")                                                     \
        for (int i = 0; i < BLOADS; ++i) {                                    \
            const int row = srow_a + i * 64;                                  \
            const int gs  = sslot ^ (row & 7);                                \
            gload16(B + (long)(n0 + row) * ldb + (K0) + gs * 8,               \
                    &Bs[BUF][(wv * 64 + i * 512) * 8]);                       \
        }                                                                     \
    }

    const int fr = lane & 15, k4 = lane >> 4;
    const int nt = K / 64;
    int cur = 0;

    STAGE(0, 0);
    __syncthreads();

    for (int t = 0; t < nt; ++t) {
        if (t + 1 < nt) STAGE(cur ^ 1, (t + 1) * 64);
#pragma unroll
        for (int ks = 0; ks < 2; ++ks) {
            bf16x8 af[MR], bf[NR];
#pragma unroll
            for (int i = 0; i < MR; ++i) {
                const int r = wr * WVM + i * 16 + fr;
                af[i] = *(const bf16x8*)&As[cur][r * 64 + ((ks * 4 + k4) ^ (r & 7)) * 8];
            }
#pragma unroll
            for (int j = 0; j < NR; ++j) {
                const int r = wc * WVN + j * 16 + fr;
                bf[j] = *(const bf16x8*)&Bs[cur][r * 64 + ((ks * 4 + k4) ^ (r & 7)) * 8];
            }
#pragma unroll
            for (int i = 0; i < MR; ++i)
#pragma unroll
                for (int j = 0; j < NR; ++j)
                    acc[i][j] = __builtin_amdgcn_mfma_f32_16x16x32_bf16(
                        af[i], bf[j], acc[i][j], 0, 0, 0);
        }
        __syncthreads();
        cur ^= 1;
    }
#undef STAGE

    const int cr4 = (lane >> 4) * 4, cc = lane & 15;
#pragma unroll
    for (int i = 0; i < MR; ++i)
#pragma unroll
        for (int j = 0; j < NR; ++j) {
            const int col = n0 + wc * WVN + j * 16 + cc;
#pragma unroll
            for (int r = 0; r < 4; ++r) {
                const int row = m0 + wr * WVM + i * 16 + cr4 + r;
                float v = acc[i][j][r];
                if (GELU) v = 0.5f * v * (1.0f + erff(v * 0.70710678118654752f));
                CT* p = &C[(long)row * ldc + col];
                if constexpr (ACCUM) *p = *p + (CT)v;
                else if constexpr (sizeof(CT) == 2) *p = __float2bfloat16(v);
                else *p = (CT)v;
            }
        }
}

// ---------------------------------------------------------------------------
// 128^2 MFMA kernels (patch embed, sim, cons) — verified round-3 versions
// ---------------------------------------------------------------------------
__device__ __forceinline__ void mfma_kloop(
    const __hip_bfloat16* __restrict__ A, int lda,
    const __hip_bfloat16* __restrict__ B, int ldb,
    int m0, int n0, int K, short* As, short* Bs,
    f32x4 acc[4][4], int wave, int lane)
{
    const int srow_in = lane >> 2;
    const int sslot   = lane & 3;
    const int wm = (wave >> 1) * 64, wn = (wave & 1) * 64;

    for (int k0 = 0; k0 < K; k0 += 32) {
        __syncthreads();
#pragma unroll
        for (int c = 0; c < 2; ++c) {
            const int rbase = c * 64 + wave * 16;
            const int row   = rbase + srow_in;
            const int gk    = sslot ^ ((row >> 1) & 3);
            gload16(A + (long)(m0 + row) * lda + k0 + gk * 8, As + rbase * 32);
            gload16(B + (long)(n0 + row) * ldb + k0 + gk * 8, Bs + rbase * 32);
        }
        __syncthreads();

        const int fr = lane & 15, ksub = lane >> 4;
        bf16x8 af[4], bfr[4];
#pragma unroll
        for (int i = 0; i < 4; ++i) {
            const int ra = wm + i * 16 + fr;
            af[i]  = *(const bf16x8*)(As + ra * 32 + (ksub ^ ((ra >> 1) & 3)) * 8);
            const int rb = wn + i * 16 + fr;
            bfr[i] = *(const bf16x8*)(Bs + rb * 32 + (ksub ^ ((rb >> 1) & 3)) * 8);
        }
#pragma unroll
        for (int i = 0; i < 4; ++i)
#pragma unroll
            for (int j = 0; j < 4; ++j)
                acc[i][j] = __builtin_amdgcn_mfma_f32_16x16x32_bf16(
                    af[i], bfr[j], acc[i][j], 0, 0, 0);
    }
}

template<typename CT, bool GELU, bool ACCUM>
__global__ __launch_bounds__(256) void gemm_mfma(
    const __hip_bfloat16* __restrict__ A, int lda, long az,
    const __hip_bfloat16* __restrict__ B, int ldb, long bz,
    CT* __restrict__ C, int ldc, long cz, int K,
    const float* __restrict__ bias)
{
    __shared__ short As[128 * 32];
    __shared__ short Bs[128 * 32];
    const int tid = threadIdx.x;
    const int wave = tid >> 6, lane = tid & 63;
    const int z = blockIdx.z;
    A += (long)z * az;  B += (long)z * bz;  C += (long)z * cz;
    const int m0 = blockIdx.y * 128, n0 = blockIdx.x * 128;
    const int wm = (wave >> 1) * 64, wn = (wave & 1) * 64;

    f32x4 acc[4][4] = {};
    mfma_kloop(A, lda, B, ldb, m0, n0, K, As, Bs, acc, wave, lane);

    const int cr = lane >> 4, cc = lane & 15;
#pragma unroll
    for (int j = 0; j < 4; ++j) {
        const int col = n0 + wn + j * 16 + cc;
        const float bv = bias ? bias[col] : 0.f;
#pragma unroll
        for (int i = 0; i < 4; ++i)
#pragma unroll
            for (int r = 0; r < 4; ++r) {
                const int row = m0 + wm + i * 16 + cr * 4 + r;
                float v = acc[i][j][r] + bv;
                if (GELU) v = 0.5f * v * (1.0f + erff(v * 0.70710678118654752f));
                CT* p = &C[(long)row * ldc + col];
                if constexpr (ACCUM) *p = *p + (CT)v;
                else if constexpr (sizeof(CT) == 2) *p = __float2bfloat16(v);
                else *p = (CT)v;
            }
    }
}

__global__ __launch_bounds__(256) void sim_mfma(
    const __hip_bfloat16* __restrict__ lev_bf, const float* __restrict__ invn,
    float* __restrict__ sim)
{
    __shared__ short As[128 * 32];
    __shared__ short Bs[128 * 32];
    const int tid = threadIdx.x;
    const int wave = tid >> 6, lane = tid & 63;
    const int z = blockIdx.z;
    const int b = z / 6, l = z - 6 * b;
    const __hip_bfloat16* base = lev_bf + (long)b * (N_ * L_ * D_) + (long)l * D_;
    const int m0 = blockIdx.y * 128, n0 = blockIdx.x * 128;
    const int wm = (wave >> 1) * 64, wn = (wave & 1) * 64;

    f32x4 acc[4][4] = {};
    mfma_kloop(base, L_ * D_, base, L_ * D_, m0, n0, D_, As, Bs, acc, wave, lane);

    const int cr = lane >> 4, cc = lane & 15;
    const float sc = 0.044194173824159216f;
#pragma unroll
    for (int j = 0; j < 4; ++j) {
        const int jg = n0 + wn + j * 16 + cc;
        const float iv = invn[((long)b * N_ + jg) * L_ + l] * sc;
#pragma unroll
        for (int i = 0; i < 4; ++i)
#pragma unroll
            for (int r = 0; r < 4; ++r) {
                const int ig = m0 + wm + i * 16 + cr * 4 + r;
                float v = acc[i][j][r] * iv;
                if (ig == jg) v = -0.0005f;
                sim[((long)z * N_ + ig) * N_ + jg] = v;
            }
    }
}

__global__ __launch_bounds__(256) void cons_mfma(
    const __hip_bfloat16* __restrict__ attn, const __hip_bfloat16* __restrict__ levT,
    float* __restrict__ cons)
{
    __shared__ short As[128 * 32];
    __shared__ short Bs[128 * 32];
    const int tid = threadIdx.x;
    const int wave = tid >> 6, lane = tid & 63;
    const int z = blockIdx.z;
    const int b = z / 6, l = z - 6 * b;
    const __hip_bfloat16* A = attn + (long)z * N_ * N_;
    const __hip_bfloat16* B = levT + (long)z * D_ * N_;
    float* C = cons + (long)b * (N_ * L_ * D_) + (long)l * D_;
    const int m0 = blockIdx.y * 128, n0 = blockIdx.x * 128;
    const int wm = (wave >> 1) * 64, wn = (wave & 1) * 64;

    f32x4 acc[4][4] = {};
    mfma_kloop(A, N_, B, N_, m0, n0, N_, As, Bs, acc, wave, lane);

    const int cr = lane >> 4, cc = lane & 15;
#pragma unroll
    for (int j = 0; j < 4; ++j) {
        const int col = n0 + wn + j * 16 + cc;
#pragma unroll
        for (int i = 0; i < 4; ++i)
#pragma unroll
            for (int r = 0; r < 4; ++r) {
                const int row = m0 + wm + i * 16 + cr * 4 + r;
                C[(long)row * (L_ * D_) + col] = acc[i][j][r];
            }
    }
}

// ---------------------------------------------------------------------------
// helper / elementwise kernels
// ---------------------------------------------------------------------------
__global__ __launch_bounds__(256) void transpose_to_bf16(
    const float* __restrict__ src, __hip_bfloat16* __restrict__ dst,
    int R, int Cc)
{
    __shared__ float t[32][33];
    const int zz = blockIdx.z;
    src += (long)zz * R * Cc;  dst += (long)zz * R * Cc;
    const int tx = threadIdx.x & 31, ty = threadIdx.x >> 5;
    const int c0 = blockIdx.x * 32, r0 = blockIdx.y * 32;
#pragma unroll
    for (int i = 0; i < 4; ++i)
        t[ty + i * 8][tx] = src[(long)(r0 + ty + i * 8) * Cc + c0 + tx];
    __syncthreads();
#pragma unroll
    for (int i = 0; i < 4; ++i)
        dst[(long)(c0 + ty + i * 8) * R + r0 + tx] = __float2bfloat16(t[tx][ty + i * 8]);
}

__global__ __launch_bounds__(256) void levT_kernel(
    const float* __restrict__ levels, __hip_bfloat16* __restrict__ levT)
{
    __shared__ float t[32][33];
    const int z = blockIdx.z;
    const int b = z / 6, l = z - 6 * b;
    const float* base = levels + (long)b * (N_ * L_ * D_) + (long)l * D_;
    const int tx = threadIdx.x & 31, ty = threadIdx.x >> 5;
    const int d0 = blockIdx.x * 32, j0 = blockIdx.y * 32;
#pragma unroll
    for (int i = 0; i < 4; ++i)
        t[ty + i * 8][tx] = base[(long)(j0 + ty + i * 8) * (L_ * D_) + d0 + tx];
    __syncthreads();
#pragma unroll
    for (int i = 0; i < 4; ++i)
        levT[(long)z * D_ * N_ + (long)(d0 + ty + i * 8) * N_ + j0 + tx] =
            __float2bfloat16(t[tx][ty + i * 8]);
}

__global__ __launch_bounds__(256) void invnorm_kernel(
    const float* __restrict__ levels, float* __restrict__ invn)
{
    const int wid = blockIdx.x * 4 + (threadIdx.x >> 6);
    const int lane = threadIdx.x & 63;
    const float* row = levels + (long)wid * 512;
    float s = 0.f;
#pragma unroll
    for (int k = lane * 4; k < 512; k += 256) {
        const float4 v = *(const float4*)&row[k];
        s += v.x * v.x + v.y * v.y + v.z * v.z + v.w * v.w;
    }
#pragma unroll
    for (int o = 1; o < 64; o <<= 1) s += __shfl_xor(s, o);
    if (lane == 0) invn[wid] = 1.0f / fmaxf(sqrtf(s), 1e-12f);
}

__global__ __launch_bounds__(256) void softmax_kernel(
    const float* __restrict__ sim, __hip_bfloat16* __restrict__ attn)
{
    const long row = (long)blockIdx.x * 4 + (threadIdx.x >> 6);
    const int lane = threadIdx.x & 63;
    const float* p = sim + row * 256;
    float4 v = *(const float4*)&p[lane * 4];
    float m = fmaxf(fmaxf(v.x, v.y), fmaxf(v.z, v.w));
#pragma unroll
    for (int o = 1; o < 64; o <<= 1) m = fmaxf(m, __shfl_xor(m, o));
    v.x = expf(v.x - m); v.y = expf(v.y - m);
    v.z = expf(v.z - m); v.w = expf(v.w - m);
    float s = v.x + v.y + v.z + v.w;
#pragma unroll
    for (int o = 1; o < 64; o <<= 1) s += __shfl_xor(s, o);
    const float inv = 1.0f / s;
    *(bf16x4s*)&attn[row * 256 + lane * 4] =
        to_bf4(v.x * inv, v.y * inv, v.z * inv, v.w * inv);
}

__global__ __launch_bounds__(256) void patchify_kernel(
    const float* __restrict__ img, __hip_bfloat16* __restrict__ Xp)
{
    const int t = blockIdx.x;
    const int b = t >> 8, n = t & 255;
    const int hh = n >> 4, ww = n & 15;
    for (int k = threadIdx.x; k < 608; k += 256) {
        float v = 0.f;
        if (k < 588) {
            const int c = k % 3;
            const int pj = (k / 3) % 14;
            const int pi = k / 42;
            v = img[(((long)b * 3 + c) * 224 + (hh * 14 + pi)) * 224 + (ww * 14 + pj)];
        }
        Xp[(long)t * 608 + k] = __float2bfloat16(v);
    }
}

__global__ __launch_bounds__(256) void wpT_kernel(
    const float* __restrict__ Wp, __hip_bfloat16* __restrict__ WpT)
{
    __shared__ float t[32][33];
    const int k0 = blockIdx.x * 32, d0 = blockIdx.y * 32;
    const int tx = threadIdx.x & 31, ty = threadIdx.x >> 5;
#pragma unroll
    for (int i = 0; i < 4; ++i) {
        const int k = k0 + ty + i * 8;
        t[ty + i * 8][tx] = (k < 588) ? Wp[(long)k * 512 + d0 + tx] : 0.f;
    }
    __syncthreads();
#pragma unroll
    for (int i = 0; i < 4; ++i)
        WpT[(long)(d0 + ty + i * 8) * 608 + k0 + tx] = __float2bfloat16(t[tx][ty + i * 8]);
}

__global__ __launch_bounds__(256) void init_levels_kernel(
    float* __restrict__ levels, const float* __restrict__ initlv)
{
    const long f = (long)blockIdx.x * 256 + threadIdx.x;
    const int d4 = f & 127;
    const int l = (int)((f >> 7) % 6);
    *(float4*)&levels[f * 4] = *(const float4*)&initlv[(long)l * 512 + d4 * 4];
}

__global__ __launch_bounds__(256) void lev_lp_init(
    const float* __restrict__ levels, const float* __restrict__ pos,
    __hip_bfloat16* __restrict__ lev_bf, __hip_bfloat16* __restrict__ lp_bf)
{
    const long f = (long)blockIdx.x * 256 + threadIdx.x;
    const int d4 = f & 127;
    const long tl = f >> 7;
    const int l = (int)(tl % 6);
    const long t = tl / 6;
    const float4 v = *(const float4*)&levels[f * 4];
    *(bf16x4s*)&lev_bf[f * 4] = to_bf4(v.x, v.y, v.z, v.w);
    if (l >= 1) {
        const float4 p = *(const float4*)&pos[(long)(t & 255) * 512 + d4 * 4];
        *(bf16x4s*)&lp_bf[((t * 5 + l - 1) * 512) + d4 * 4] =
            to_bf4(v.x + p.x, v.y + p.y, v.z + p.z, v.w + p.w);
    }
}

__global__ __launch_bounds__(256) void zero_l0(float* __restrict__ acc)
{
    const long f = (long)blockIdx.x * 256 + threadIdx.x;
    const long t = f >> 7;
    const int d4 = (int)(f & 127);
    *(float4*)&acc[t * 3072 + d4 * 4] = make_float4(0.f, 0.f, 0.f, 0.f);
}

// one WAVE per (t,l) row: levels update + bf16 copies + invnorm for NEXT iter
__global__ __launch_bounds__(256) void update_kernel(
    float* __restrict__ levels, const float* __restrict__ tokens,
    const float* __restrict__ acc, const float* __restrict__ cons,
    const float* __restrict__ pos,
    __hip_bfloat16* __restrict__ lev_bf, __hip_bfloat16* __restrict__ lp_bf,
    float* __restrict__ invn)
{
    const int wid = blockIdx.x * 4 + (threadIdx.x >> 6);   // row t*6+l
    const int lane = threadIdx.x & 63;
    const int l = wid % 6;
    const long t = wid / 6;
    const long rowoff = (long)wid * 512;

    float ss = 0.f;
    float4 outv[2];
#pragma unroll
    for (int half = 0; half < 2; ++half) {
        const int k = lane * 4 + half * 256;
        const long off = rowoff + k;
        float4 lev = *(const float4*)&levels[off];
        const float4 cns = *(const float4*)&cons[off];
        float4 ac  = *(const float4*)&acc[off];
        if (l == 0) {
            const float4 bot = *(const float4*)&tokens[t * 512 + k];
            ac.x += bot.x; ac.y += bot.y; ac.z += bot.z; ac.w += bot.w;
        }
        lev.x = (lev.x + ac.x + cns.x) * 0.25f;
        lev.y = (lev.y + ac.y + cns.y) * 0.25f;
        lev.z = (lev.z + ac.z + cns.z) * 0.25f;
        lev.w = (lev.w + ac.w + cns.w) * 0.25f;
        *(float4*)&levels[off] = lev;
        *(bf16x4s*)&lev_bf[off] = to_bf4(lev.x, lev.y, lev.z, lev.w);
        if (l >= 1) {
            const float4 p = *(const float4*)&pos[(long)(t & 255) * 512 + k];
            *(bf16x4s*)&lp_bf[((t * 5 + l - 1) * 512) + k] =
                to_bf4(lev.x + p.x, lev.y + p.y, lev.z + p.z, lev.w + p.w);
        }
        ss += lev.x * lev.x + lev.y * lev.y + lev.z * lev.z + lev.w * lev.w;
        outv[half] = lev;
    }
    (void)outv;
#pragma unroll
    for (int o = 1; o < 64; o <<= 1) ss += __shfl_xor(ss, o);
    if (lane == 0) invn[wid] = 1.0f / fmaxf(sqrtf(ss), 1e-12f);
}

extern "C" void kernel_launch(void* const* d_in, const int* in_sizes, int n_in,
                              void* d_out, int out_size, void* d_ws, size_t ws_size,
                              hipStream_t stream)
{
    const float* img    = (const float*)d_in[0];
    const float* Wp     = (const float*)d_in[1];
    const float* bp     = (const float*)d_in[2];
    const float* pos    = (const float*)d_in[3];
    const float* initlv = (const float*)d_in[4];
    const float* bu_in  = (const float*)d_in[5];
    const float* bu_out = (const float*)d_in[6];
    const float* td_in  = (const float*)d_in[7];
    const float* td_out = (const float*)d_in[8];

    float* levels = (float*)d_out;                 // [2048][6][512] fp32
    float* ws = (float*)d_ws;
    float* tokens  = ws;                           // 1,048,576 f
    float* acc     = tokens + 1048576;             // 6,291,456 f
    float* overlay = acc + 6291456;                // 10,485,760 f (h | sim+cons)
    float* invn    = overlay + 10485760;           // 12,288 f
    __hip_bfloat16* lev_bf  = (__hip_bfloat16*)(invn + 12288);   // 6,291,456 bf16
    __hip_bfloat16* lp_bf   = lev_bf + 6291456;                  // 5,242,880
    __hip_bfloat16* wtin_bu = lp_bf + 5242880;                   // 5,242,880
    __hip_bfloat16* wtout_bu= wtin_bu + 5242880;                 // 5,242,880
    __hip_bfloat16* wtin_td = wtout_bu + 5242880;                // 5,242,880
    __hip_bfloat16* wtout_td= wtin_td + 5242880;                 // 5,242,880

    __hip_bfloat16* h = (__hip_bfloat16*)overlay;  // [5][2048][2048] bf16
    float* sim  = overlay;                         // [48][256][256] f
    float* cons = overlay + 3145728;               // [2048][6][512] f
    __hip_bfloat16* levT_bf = lev_bf;              // [48][512][256] (alias)
    __hip_bfloat16* attn_bf = lp_bf;               // [48][256][256] (alias)
    __hip_bfloat16* Xp  = (__hip_bfloat16*)acc;    // [2048][608] (dead until FF2)
    __hip_bfloat16* WpT = Xp + 1245184;            // [512][608]

    init_levels_kernel<<<6144, 256, 0, stream>>>(levels, initlv);
    lev_lp_init<<<6144, 256, 0, stream>>>(levels, pos, lev_bf, lp_bf);
    invnorm_kernel<<<3072, 256, 0, stream>>>(levels, invn);   // iter-0 norms
    patchify_kernel<<<NT_, 256, 0, stream>>>(img, Xp);
    wpT_kernel<<<dim3(19, 16), 256, 0, stream>>>(Wp, WpT);
    gemm_mfma<float, false, false><<<dim3(4, 16, 1), 256, 0, stream>>>(
        Xp, 608, 0, WpT, 608, 0, tokens, 512, 0, 608, bp);
    transpose_to_bf16<<<dim3(64, 16, 5), 256, 0, stream>>>(bu_in,  wtin_bu,  512, 2048);
    transpose_to_bf16<<<dim3(16, 64, 5), 256, 0, stream>>>(bu_out, wtout_bu, 2048, 512);
    transpose_to_bf16<<<dim3(64, 16, 5), 256, 0, stream>>>(td_in,  wtin_td,  512, 2048);
    transpose_to_bf16<<<dim3(16, 64, 5), 256, 0, stream>>>(td_out, wtout_td, 2048, 512);

    for (int it = 0; it < 12; ++it) {
        // FF1-bu: h[z] = gelu(lev[:,z,:] @ w)    M=2048 N=2048 K=512
        gemm_ff<128, 128, 2, 4, __hip_bfloat16, true, false>
            <<<dim3(16, 16, 5), 512, 0, stream>>>(
            lev_bf, L_ * D_, 512,
            wtin_bu, D_, (long)HID_ * D_,
            h, HID_, (long)NT_ * HID_, D_);
        // FF2-bu: acc[:, z+1] = h[z] @ w2        M=2048 N=512 K=2048
        gemm_ff<128, 128, 2, 4, float, false, false>
            <<<dim3(4, 16, 5), 512, 0, stream>>>(
            h, HID_, (long)NT_ * HID_,
            wtout_bu, HID_, (long)D_ * HID_,
            acc + D_, L_ * D_, D_, HID_);
        zero_l0<<<1024, 256, 0, stream>>>(acc);
        // FF1-td: h[z] = gelu((lev[:,z+1,:]+pos) @ w)
        gemm_ff<128, 128, 2, 4, __hip_bfloat16, true, false>
            <<<dim3(16, 16, 5), 512, 0, stream>>>(
            lp_bf, 5 * D_, 512,
            wtin_td, D_, (long)HID_ * D_,
            h, HID_, (long)NT_ * HID_, D_);
        // FF2-td: acc[:, z] += h[z] @ w2
        gemm_ff<128, 128, 2, 4, float, false, true>
            <<<dim3(4, 16, 5), 512, 0, stream>>>(
            h, HID_, (long)NT_ * HID_,
            wtout_td, HID_, (long)D_ * HID_,
            acc, L_ * D_, D_, HID_);

        sim_mfma<<<dim3(2, 2, 48), 256, 0, stream>>>(lev_bf, invn, sim);
        softmax_kernel<<<3072, 256, 0, stream>>>(sim, attn_bf);
        levT_kernel<<<dim3(16, 8, 48), 256, 0, stream>>>(levels, levT_bf);
        cons_mfma<<<dim3(4, 2, 48), 256, 0, stream>>>(attn_bf, levT_bf, cons);
        update_kernel<<<3072, 256, 0, stream>>>(levels, tokens, acc, cons, pos,
                                                lev_bf, lp_bf, invn);
    }
}